// Round 2
// 10502.197 us; speedup vs baseline: 2.3139x; 2.3139x over previous
//
#include <hip/hip_runtime.h>
#include <math.h>

#define B   64
#define TS  64
#define TT  64
#define E   512
#define H   512
#define DH  1024
#define VT  32000
#define NPART 1024           // stride for loss partials (1000 used)

typedef __attribute__((ext_vector_type(8))) short short8;
typedef __attribute__((ext_vector_type(4))) float floatx4;

__device__ __forceinline__ ushort f2bf(float f) {
    union { float f; unsigned int i; } v; v.f = f;
    unsigned int u = v.i;
    return (ushort)((u + 0x7fffu + ((u >> 16) & 1u)) >> 16);
}
// gather-convert 8 contiguous f32 -> bf16 fragment (only used for emb gather)
__device__ __forceinline__ short8 ld8bf(const float* p) {
    short8 r;
#pragma unroll
    for (int i = 0; i < 8; i++) r[i] = (short)f2bf(p[i]);
    return r;
}
__device__ __forceinline__ short8 ld8h(const ushort* p) {
    return *(const short8*)p;
}
__device__ __forceinline__ float sigm(float x) { return 1.0f / (1.0f + expf(-x)); }

// ---------------------------------------------------------------------------
// one-time f32 -> bf16 tensor conversion (vectorized, grid-stride)
// ---------------------------------------------------------------------------
__global__ void conv_bf16(const float* __restrict__ src, ushort* __restrict__ dst, int n4)
{
    int i = blockIdx.x * 256 + threadIdx.x;
    int stride = gridDim.x * 256;
    for (; i < n4; i += stride) {
        float4 v = ((const float4*)src)[i];
        ushort4 o;
        o.x = f2bf(v.x); o.y = f2bf(v.y); o.z = f2bf(v.z); o.w = f2bf(v.w);
        ((ushort4*)dst)[i] = o;
    }
}

// ---------------------------------------------------------------------------
// GEMM: C[M=64,N] = A[M,K](bf16) * W[N,K](bf16)^T + bias.
// Block = 4 waves (2x2), block tile 64x64, wave tile 32x32 (2x2 MFMA).
// outf (f32) and/or outb (bf16, optional tanh) may be null.
// MFMA layouts (HW-verified m89): A/B frag row=lane&15, k=(lane>>4)*8+j;
// C/D row=(lane>>4)*4+r, col=lane&15.
// ---------------------------------------------------------------------------
__global__ __launch_bounds__(256) void gemm_bt(
    const ushort* __restrict__ A, const ushort* __restrict__ W,
    const float* __restrict__ bias, int K,
    float* __restrict__ outf, int ldof,
    ushort* __restrict__ outb, int ldob, int do_tanh)
{
    const int tid  = threadIdx.x;
    const int wave = tid >> 6;
    const int lane = tid & 63;
    const int wm = wave >> 1, wn = wave & 1;
    const int l15 = lane & 15, quad = lane >> 4;
    const int m0 = wm * 32;
    const int n0 = blockIdx.x * 64 + wn * 32;
    const int koff = quad * 8;

    floatx4 acc[2][2] = {};
    const ushort* Ap0 = A + (size_t)(m0 + l15) * K + koff;
    const ushort* Ap1 = Ap0 + (size_t)16 * K;
    const ushort* Wp0 = W + (size_t)(n0 + l15) * K + koff;
    const ushort* Wp1 = Wp0 + (size_t)16 * K;
#pragma unroll 2
    for (int kb = 0; kb < K; kb += 32) {
        short8 a0 = ld8h(Ap0 + kb);
        short8 a1 = ld8h(Ap1 + kb);
        short8 w0 = ld8h(Wp0 + kb);
        short8 w1 = ld8h(Wp1 + kb);
        acc[0][0] = __builtin_amdgcn_mfma_f32_16x16x32_bf16(a0, w0, acc[0][0], 0, 0, 0);
        acc[0][1] = __builtin_amdgcn_mfma_f32_16x16x32_bf16(a0, w1, acc[0][1], 0, 0, 0);
        acc[1][0] = __builtin_amdgcn_mfma_f32_16x16x32_bf16(a1, w0, acc[1][0], 0, 0, 0);
        acc[1][1] = __builtin_amdgcn_mfma_f32_16x16x32_bf16(a1, w1, acc[1][1], 0, 0, 0);
    }
    for (int i = 0; i < 2; i++)
        for (int j = 0; j < 2; j++) {
            int col = n0 + j * 16 + l15;
            float bv = bias ? bias[col] : 0.0f;
            for (int r = 0; r < 4; r++) {
                int row = m0 + i * 16 + quad * 4 + r;
                float v = acc[i][j][r] + bv;
                if (outf) outf[(size_t)row * ldof + col] = v;
                if (outb) outb[(size_t)row * ldob + col] = f2bf(do_tanh ? tanhf(v) : v);
            }
        }
}

// ---------------------------------------------------------------------------
// Encoder step, both directions: gates = sv[t] @ Wih^T + h_prev @ Whh^T + b,
// then LSTM cell. All MFMA operands preconverted bf16 (16B vector loads).
// Grid: 64 blocks (dir = bid>>5, jt = bid&31). Wave w = gate w, cols 16.
// ---------------------------------------------------------------------------
__global__ __launch_bounds__(256) void enc_step(
    const ushort* __restrict__ Wih_f, const ushort* __restrict__ Whh_f,
    const float* __restrict__ bias_f,
    const ushort* __restrict__ Wih_r, const ushort* __restrict__ Whh_r,
    const float* __restrict__ bias_r,
    const ushort* __restrict__ sv,                       // [TS][B][E] bf16
    const ushort* __restrict__ hprev, ushort* __restrict__ hnext,  // [dir][B][H] bf16
    const float* __restrict__ cprev, float* __restrict__ cnext,
    float* __restrict__ Henc, ushort* __restrict__ final_bf,
    const int* __restrict__ src_lens, int t)
{
    const int d  = blockIdx.x >> 5;
    const int jt = blockIdx.x & 31;
    const int tid = threadIdx.x;
    const int wave = tid >> 6, lane = tid & 63;
    const int l15 = lane & 15, quad = lane >> 4;
    const ushort* Wih  = d ? Wih_r : Wih_f;
    const ushort* Whh  = d ? Whh_r : Whh_f;
    const float*  bias = d ? bias_r : bias_f;
    const ushort* hp = hprev + (size_t)d * (B * H);
    const int n0 = wave * H + jt * 16;      // column in 4H gate space
    const int koff = quad * 8;

    floatx4 acc[4] = {};
    const ushort* Wp = Wih + (size_t)(n0 + l15) * E + koff;
    const ushort* Ap = sv + (size_t)t * B * E + koff;
#pragma unroll 2
    for (int kb = 0; kb < E; kb += 32) {
        short8 w = ld8h(Wp + kb);
#pragma unroll
        for (int mi = 0; mi < 4; mi++) {
            short8 a = ld8h(Ap + (size_t)(mi * 16 + l15) * E + kb);
            acc[mi] = __builtin_amdgcn_mfma_f32_16x16x32_bf16(a, w, acc[mi], 0, 0, 0);
        }
    }
    const ushort* Wp2 = Whh + (size_t)(n0 + l15) * H + koff;
#pragma unroll 2
    for (int kb = 0; kb < H; kb += 32) {
        short8 w = ld8h(Wp2 + kb);
#pragma unroll
        for (int mi = 0; mi < 4; mi++) {
            short8 a = ld8h(hp + (size_t)(mi * 16 + l15) * H + kb + koff);
            acc[mi] = __builtin_amdgcn_mfma_f32_16x16x32_bf16(a, w, acc[mi], 0, 0, 0);
        }
    }

    __shared__ float gl[4][B][16];
    float bv = bias[n0 + l15];
    for (int mi = 0; mi < 4; mi++)
        for (int r = 0; r < 4; r++) {
            int b_ = mi * 16 + quad * 4 + r;
            gl[wave][b_][l15] = acc[mi][r] + bv;
        }
    __syncthreads();

    for (int p = tid; p < B * 16; p += 256) {
        int b_ = p >> 4, jl = p & 15;
        int j = jt * 16 + jl;
        float gi = gl[0][b_][jl], gf = gl[1][b_][jl];
        float gg = gl[2][b_][jl], go = gl[3][b_][jl];
        float cp = cprev[((size_t)d * B + b_) * H + j];
        float cn = sigm(gf) * cp + sigm(gi) * tanhf(gg);
        float hn = sigm(go) * tanhf(cn);
        cnext[((size_t)d * B + b_) * H + j] = cn;
        hnext[((size_t)d * B + b_) * H + j] = f2bf(hn);
        Henc[(size_t)(b_ * TS + t) * DH + d * H + j] = hn;
        if (t == src_lens[b_] - 1) {
            final_bf[b_ * (4 * H) + d * H + j] = f2bf(hn);           // H part
            final_bf[b_ * (4 * H) + 2 * H + d * H + j] = f2bf(cn);   // C part
        }
    }
}

// ---------------------------------------------------------------------------
// Decoder gates GEMM: A row b = [emb(trg_tok[b,t]) | av_bf[b] | h_bf[b]],
// W = [dec_Wih(bf16) | dec_Whh(bf16)]. gates[b, 4096] f32. Grid 64 blocks.
// ---------------------------------------------------------------------------
__global__ __launch_bounds__(256) void dec_gates(
    const float* __restrict__ trg_emb, const int* __restrict__ trg_tokens,
    const ushort* __restrict__ av, const ushort* __restrict__ hbf,
    const ushort* __restrict__ Wih, const ushort* __restrict__ Whh,
    const float* __restrict__ bias, float* __restrict__ gates, int t)
{
    const int tid = threadIdx.x;
    const int wave = tid >> 6, lane = tid & 63;
    const int wm = wave >> 1, wn = wave & 1;
    const int l15 = lane & 15, quad = lane >> 4;
    const int m0 = wm * 32;
    const int n0 = blockIdx.x * 64 + wn * 32;
    const int koff = quad * 8;
    const int b0 = m0 + l15, b1 = m0 + 16 + l15;

    const float* e0 = trg_emb + (size_t)trg_tokens[b0 * TT + t] * E + koff;
    const float* e1 = trg_emb + (size_t)trg_tokens[b1 * TT + t] * E + koff;
    const ushort* w0p = Wih + (size_t)(n0 + l15) * 1536 + koff;
    const ushort* w1p = w0p + (size_t)16 * 1536;

    floatx4 acc[2][2] = {};
    // segment 1: embedding (f32 gather + convert), k in [0, 512)
#pragma unroll 2
    for (int kb = 0; kb < E; kb += 32) {
        short8 a0 = ld8bf(e0 + kb);
        short8 a1 = ld8bf(e1 + kb);
        short8 w0 = ld8h(w0p + kb);
        short8 w1 = ld8h(w1p + kb);
        acc[0][0] = __builtin_amdgcn_mfma_f32_16x16x32_bf16(a0, w0, acc[0][0], 0, 0, 0);
        acc[0][1] = __builtin_amdgcn_mfma_f32_16x16x32_bf16(a0, w1, acc[0][1], 0, 0, 0);
        acc[1][0] = __builtin_amdgcn_mfma_f32_16x16x32_bf16(a1, w0, acc[1][0], 0, 0, 0);
        acc[1][1] = __builtin_amdgcn_mfma_f32_16x16x32_bf16(a1, w1, acc[1][1], 0, 0, 0);
    }
    // segment 2: av (bf16), Wih cols [512, 1536)
    const ushort* a0p = av + (size_t)b0 * DH + koff;
    const ushort* a1p = av + (size_t)b1 * DH + koff;
#pragma unroll 2
    for (int kb = 0; kb < DH; kb += 32) {
        short8 a0 = ld8h(a0p + kb);
        short8 a1 = ld8h(a1p + kb);
        short8 w0 = ld8h(w0p + E + kb);
        short8 w1 = ld8h(w1p + E + kb);
        acc[0][0] = __builtin_amdgcn_mfma_f32_16x16x32_bf16(a0, w0, acc[0][0], 0, 0, 0);
        acc[0][1] = __builtin_amdgcn_mfma_f32_16x16x32_bf16(a0, w1, acc[0][1], 0, 0, 0);
        acc[1][0] = __builtin_amdgcn_mfma_f32_16x16x32_bf16(a1, w0, acc[1][0], 0, 0, 0);
        acc[1][1] = __builtin_amdgcn_mfma_f32_16x16x32_bf16(a1, w1, acc[1][1], 0, 0, 0);
    }
    // segment 3: h (hbf[:, :DH]) with Whh
    const ushort* h0p = hbf + (size_t)b0 * (2 * DH) + koff;
    const ushort* h1p = hbf + (size_t)b1 * (2 * DH) + koff;
    const ushort* v0p = Whh + (size_t)(n0 + l15) * DH + koff;
    const ushort* v1p = v0p + (size_t)16 * DH;
#pragma unroll 2
    for (int kb = 0; kb < DH; kb += 32) {
        short8 a0 = ld8h(h0p + kb);
        short8 a1 = ld8h(h1p + kb);
        short8 w0 = ld8h(v0p + kb);
        short8 w1 = ld8h(v1p + kb);
        acc[0][0] = __builtin_amdgcn_mfma_f32_16x16x32_bf16(a0, w0, acc[0][0], 0, 0, 0);
        acc[0][1] = __builtin_amdgcn_mfma_f32_16x16x32_bf16(a0, w1, acc[0][1], 0, 0, 0);
        acc[1][0] = __builtin_amdgcn_mfma_f32_16x16x32_bf16(a1, w0, acc[1][0], 0, 0, 0);
        acc[1][1] = __builtin_amdgcn_mfma_f32_16x16x32_bf16(a1, w1, acc[1][1], 0, 0, 0);
    }

    for (int i = 0; i < 2; i++)
        for (int j = 0; j < 2; j++) {
            int col = n0 + j * 16 + l15;
            float bv = bias[col];
            for (int r = 0; r < 4; r++) {
                int row = m0 + i * 16 + quad * 4 + r;
                gates[(size_t)row * (4 * DH) + col] = acc[i][j][r] + bv;
            }
        }
}

// ---------------------------------------------------------------------------
// embed src tokens -> sv_bf [TS][B][E] bf16 (transposed for contiguous A rows)
// ---------------------------------------------------------------------------
__global__ void embed_src(const int* __restrict__ toks, const float* __restrict__ emb,
                          ushort* __restrict__ sv)
{
    int bt = blockIdx.x;                 // b*TS + t
    int b_ = bt >> 6, t = bt & 63;
    int tok = toks[bt];
    const float* src = emb + (size_t)tok * E;
    ushort* dst = sv + ((size_t)t * B + b_) * E;
    for (int e = threadIdx.x; e < E; e += 256) dst[e] = f2bf(src[e]);
}

// ---------------------------------------------------------------------------
// Fused decoder cell + attention. One block per batch row.
// h kept in LDS; writes h (bf16) and ctx (bf16) into hcbf = [h | ctx].
// ---------------------------------------------------------------------------
__global__ __launch_bounds__(256) void dec_cell_attn(
    const float* __restrict__ gates, float* __restrict__ c,
    ushort* __restrict__ hcbf,
    const float* __restrict__ Henc, const int* __restrict__ src_lens)
{
    int b_ = blockIdx.x, tid = threadIdx.x;
    __shared__ float hsm[DH];
    __shared__ float red[256];
    __shared__ float attn[TS];
    const float* g = gates + (size_t)b_ * 4 * DH;
    for (int j = tid; j < DH; j += 256) {
        float cn = sigm(g[DH + j]) * c[(size_t)b_ * DH + j]
                 + sigm(g[j]) * tanhf(g[2 * DH + j]);
        c[(size_t)b_ * DH + j] = cn;
        float hn = sigm(g[3 * DH + j]) * tanhf(cn);
        hsm[j] = hn;
        hcbf[(size_t)b_ * 2 * DH + j] = f2bf(hn);
    }
    __syncthreads();
    // scores[t] = h . Henc[b,t,:]  (vectorized)
    int tq = tid & 63, part = tid >> 6;
    const float4* He4 = (const float4*)(Henc + (size_t)(b_ * TS + tq) * DH + part * 256);
    const float4* h4  = (const float4*)(hsm + part * 256);
    float pp = 0.f;
#pragma unroll 8
    for (int j = 0; j < 64; j++) {
        float4 a = He4[j]; float4 hh = h4[j];
        pp += a.x * hh.x + a.y * hh.y + a.z * hh.z + a.w * hh.w;
    }
    red[tid] = pp;
    __syncthreads();
    if (tid < 64) {
        float s = red[tid] + red[tid + 64] + red[tid + 128] + red[tid + 192];
        if (tid >= src_lens[b_]) s = -1e9f;
        float m = s;
        for (int off = 32; off >= 1; off >>= 1) m = fmaxf(m, __shfl_xor(m, off));
        float e = expf(s - m);
        float sum = e;
        for (int off = 32; off >= 1; off >>= 1) sum += __shfl_xor(sum, off);
        attn[tid] = e / sum;
    }
    __syncthreads();
    // ctx[j] = sum_t attn[t] * Henc[b,t,j]
    for (int k = 0; k < 4; k++) {
        int j = k * 256 + tid;
        float a = 0.f;
#pragma unroll 8
        for (int t2 = 0; t2 < TS; t2++)
            a += attn[t2] * Henc[(size_t)(b_ * TS + t2) * DH + j];
        hcbf[(size_t)b_ * 2 * DH + DH + j] = f2bf(a);
    }
}

// ---------------------------------------------------------------------------
// Output projection GEMM with fused loss partials: never materializes logits.
// Per wave (32 cols of 64-col block tile): row-wise max & sum(exp(v-max))
// via 16-lane shuffles -> pm/ps[row][part]; gold logit captured directly.
// ---------------------------------------------------------------------------
__global__ __launch_bounds__(256) void out_gemm_loss(
    const ushort* __restrict__ A,        // av_bf [B][DH]
    const ushort* __restrict__ W,        // out_W bf16 [VT][DH]
    const float* __restrict__ bias,
    const int* __restrict__ trg_tokens,
    float* __restrict__ pm, float* __restrict__ ps, float* __restrict__ gval,
    int t)
{
    const int tid = threadIdx.x;
    const int wave = tid >> 6, lane = tid & 63;
    const int wm = wave >> 1, wn = wave & 1;
    const int l15 = lane & 15, quad = lane >> 4;
    const int m0 = wm * 32;
    const int n0 = blockIdx.x * 64 + wn * 32;
    const int koff = quad * 8;

    __shared__ int gsm[B];
    if (tid < B) gsm[tid] = trg_tokens[tid * TT + t + 1];

    floatx4 acc[2][2] = {};
    const ushort* Ap0 = A + (size_t)(m0 + l15) * DH + koff;
    const ushort* Ap1 = Ap0 + (size_t)16 * DH;
    const ushort* Wp0 = W + (size_t)(n0 + l15) * DH + koff;
    const ushort* Wp1 = Wp0 + (size_t)16 * DH;
#pragma unroll 2
    for (int kb = 0; kb < DH; kb += 32) {
        short8 a0 = ld8h(Ap0 + kb);
        short8 a1 = ld8h(Ap1 + kb);
        short8 w0 = ld8h(Wp0 + kb);
        short8 w1 = ld8h(Wp1 + kb);
        acc[0][0] = __builtin_amdgcn_mfma_f32_16x16x32_bf16(a0, w0, acc[0][0], 0, 0, 0);
        acc[0][1] = __builtin_amdgcn_mfma_f32_16x16x32_bf16(a0, w1, acc[0][1], 0, 0, 0);
        acc[1][0] = __builtin_amdgcn_mfma_f32_16x16x32_bf16(a1, w0, acc[1][0], 0, 0, 0);
        acc[1][1] = __builtin_amdgcn_mfma_f32_16x16x32_bf16(a1, w1, acc[1][1], 0, 0, 0);
    }
    __syncthreads();   // gsm visible

    const int part = blockIdx.x * 2 + wn;
    for (int i = 0; i < 2; i++) {
        float v[2][4];
        for (int j = 0; j < 2; j++) {
            int col = n0 + j * 16 + l15;
            float bv = bias[col];
            for (int r = 0; r < 4; r++) {
                v[j][r] = acc[i][j][r] + bv;
                int row = m0 + i * 16 + quad * 4 + r;
                if (col == gsm[row]) gval[row] = v[j][r];
            }
        }
        for (int r = 0; r < 4; r++) {
            float m = fmaxf(v[0][r], v[1][r]);
#pragma unroll
            for (int off = 1; off < 16; off <<= 1) m = fmaxf(m, __shfl_xor(m, off));
            float s = expf(v[0][r] - m) + expf(v[1][r] - m);
#pragma unroll
            for (int off = 1; off < 16; off <<= 1) s += __shfl_xor(s, off);
            if (l15 == 0) {
                int row = m0 + i * 16 + quad * 4 + r;
                pm[(size_t)row * NPART + part] = m;
                ps[(size_t)row * NPART + part] = s;
            }
        }
    }
}

// Combine 1000 per-block partials per row -> lse -> masked lsm value.
__global__ __launch_bounds__(256) void combine_loss(
    const float* __restrict__ pm, const float* __restrict__ ps,
    const float* __restrict__ gval, const int* __restrict__ trg_lens,
    float* __restrict__ nll_buf, int t)
{
    int b_ = blockIdx.x, tid = threadIdx.x;
    __shared__ float red[256];
    const float* pmr = pm + (size_t)b_ * NPART;
    const float* psr = ps + (size_t)b_ * NPART;
    float m = -1e30f;
    for (int p = tid; p < 1000; p += 256) m = fmaxf(m, pmr[p]);
    red[tid] = m; __syncthreads();
    for (int s = 128; s >= 1; s >>= 1) {
        if (tid < s) red[tid] = fmaxf(red[tid], red[tid + s]);
        __syncthreads();
    }
    m = red[0]; __syncthreads();
    float s = 0.f;
    for (int p = tid; p < 1000; p += 256) s += psr[p] * expf(pmr[p] - m);
    red[tid] = s; __syncthreads();
    for (int st = 128; st >= 1; st >>= 1) {
        if (tid < st) red[tid] += red[tid + st];
        __syncthreads();
    }
    if (tid == 0) {
        float lse = m + logf(red[0]);
        nll_buf[t * B + b_] = (t + 1 < trg_lens[b_]) ? (gval[b_] - lse) : 0.f;
    }
}

__global__ void init_zero(ushort* hbf, float* cbuf, ushort* avbf)
{
    int idx = blockIdx.x * 256 + threadIdx.x;   // 131072 = 2*2*B*H
    hbf[idx] = 0;
    cbuf[idx] = 0.f;
    if (idx < B * DH) avbf[idx] = 0;
}

__global__ __launch_bounds__(256) void write_out(const float* __restrict__ nll_buf,
                                                 float* __restrict__ out)
{
    __shared__ float red[256];
    float s = 0.f;
    for (int i = threadIdx.x; i < (TT - 1) * B; i += 256) s += nll_buf[i];
    red[threadIdx.x] = s; __syncthreads();
    for (int st = 128; st >= 1; st >>= 1) {
        if (threadIdx.x < st) red[threadIdx.x] += red[threadIdx.x + st];
        __syncthreads();
    }
    if (threadIdx.x == 0) out[0] = red[0];
}

// ---------------------------------------------------------------------------
extern "C" void kernel_launch(void* const* d_in, const int* in_sizes, int n_in,
                              void* d_out, int out_size, void* d_ws, size_t ws_size,
                              hipStream_t stream)
{
    const int*   src_tokens = (const int*)d_in[0];
    const int*   src_lens   = (const int*)d_in[1];
    const int*   trg_tokens = (const int*)d_in[2];
    const int*   trg_lens   = (const int*)d_in[3];
    const float* src_emb    = (const float*)d_in[4];
    const float* trg_emb    = (const float*)d_in[5];
    const float* enc_Wih    = (const float*)d_in[6];
    const float* enc_Whh    = (const float*)d_in[7];
    const float* enc_b      = (const float*)d_in[8];
    const float* rev_Wih    = (const float*)d_in[9];
    const float* rev_Whh    = (const float*)d_in[10];
    const float* rev_b      = (const float*)d_in[11];
    const float* dec_Wih    = (const float*)d_in[12];
    const float* dec_Whh    = (const float*)d_in[13];
    const float* dec_b      = (const float*)d_in[14];
    const float* hid_W      = (const float*)d_in[15];
    const float* hid_b      = (const float*)d_in[16];
    const float* out_W      = (const float*)d_in[17];
    const float* out_b      = (const float*)d_in[18];
    const float* init_W     = (const float*)d_in[19];
    const float* init_b     = (const float*)d_in[20];

    char* ws = (char*)d_ws;
    size_t off = 0;
    auto alloc = [&](size_t bytes) -> void* {
        void* p = ws + off;
        off = (off + bytes + 255) & ~(size_t)255;
        return p;
    };
    // activations / state  (~25 MB)
    ushort* sv_bf    = (ushort*)alloc((size_t)TS * B * E * 2);       // 4.2 MB
    float*  Henc     = (float*) alloc((size_t)B * TS * DH * 4);      // 16.8 MB
    ushort* hbf      = (ushort*)alloc((size_t)2 * 2 * B * H * 2);    // ping-pong
    float*  cbuf     = (float*) alloc((size_t)2 * 2 * B * H * 4);
    ushort* final_bf = (ushort*)alloc((size_t)B * 4 * H * 2);
    float*  gates    = (float*) alloc((size_t)B * 4 * DH * 4);
    float*  dec_c    = (float*) alloc((size_t)B * DH * 4);
    ushort* hc_bf    = (ushort*)alloc((size_t)B * 2 * DH * 2);       // [h | ctx]
    ushort* av_bf    = (ushort*)alloc((size_t)B * DH * 2);
    float*  pm       = (float*) alloc((size_t)B * NPART * 4);
    float*  ps       = (float*) alloc((size_t)B * NPART * 4);
    float*  gval     = (float*) alloc((size_t)B * 4);
    float*  nll_buf  = (float*) alloc((size_t)(TT - 1) * B * 4);
    // bf16 weights (~101 MB)
    ushort* w_eWih_f = (ushort*)alloc((size_t)4 * H * E * 2);
    ushort* w_eWhh_f = (ushort*)alloc((size_t)4 * H * H * 2);
    ushort* w_eWih_r = (ushort*)alloc((size_t)4 * H * E * 2);
    ushort* w_eWhh_r = (ushort*)alloc((size_t)4 * H * H * 2);
    ushort* w_dWih   = (ushort*)alloc((size_t)4 * DH * 1536 * 2);
    ushort* w_dWhh   = (ushort*)alloc((size_t)4 * DH * DH * 2);
    ushort* w_hid    = (ushort*)alloc((size_t)DH * 2 * DH * 2);
    ushort* w_out    = (ushort*)alloc((size_t)VT * DH * 2);          // 65.5 MB
    ushort* w_init   = (ushort*)alloc((size_t)DH * 2 * DH * 2);

    // one-time weight conversions
    conv_bf16<<<512, 256, 0, stream>>>(enc_Wih, w_eWih_f, 4 * H * E / 4);
    conv_bf16<<<512, 256, 0, stream>>>(enc_Whh, w_eWhh_f, 4 * H * H / 4);
    conv_bf16<<<512, 256, 0, stream>>>(rev_Wih, w_eWih_r, 4 * H * E / 4);
    conv_bf16<<<512, 256, 0, stream>>>(rev_Whh, w_eWhh_r, 4 * H * H / 4);
    conv_bf16<<<512, 256, 0, stream>>>(dec_Wih, w_dWih, 4 * DH * 1536 / 4);
    conv_bf16<<<512, 256, 0, stream>>>(dec_Whh, w_dWhh, 4 * DH * DH / 4);
    conv_bf16<<<512, 256, 0, stream>>>(hid_W, w_hid, DH * 2 * DH / 4);
    conv_bf16<<<2048, 256, 0, stream>>>(out_W, w_out, VT * DH / 4);
    conv_bf16<<<512, 256, 0, stream>>>(init_W, w_init, DH * 2 * DH / 4);

    init_zero<<<2 * 2 * B * H / 256, 256, 0, stream>>>(hbf, cbuf, av_bf);
    embed_src<<<B * TS, 256, 0, stream>>>(src_tokens, src_emb, sv_bf);

    // encoder recurrence (both directions per launch)
    for (int t = 0; t < TS; t++) {
        int par = t & 1;
        enc_step<<<64, 256, 0, stream>>>(
            w_eWih_f, w_eWhh_f, enc_b, w_eWih_r, w_eWhh_r, rev_b, sv_bf,
            hbf + (size_t)par * 2 * B * H, hbf + (size_t)(par ^ 1) * 2 * B * H,
            cbuf + (size_t)par * 2 * B * H, cbuf + (size_t)(par ^ 1) * 2 * B * H,
            Henc, final_bf, src_lens, t);
    }

    // c0 = final_cat @ init_W^T + init_b -> dec_c (f32); h0 = tanh(c0) -> hc_bf[:, :DH]
    gemm_bt<<<dim3(DH / 64), 256, 0, stream>>>(final_bf, w_init, init_b, 2 * DH,
                                               dec_c, DH, hc_bf, 2 * DH, 1);

    // decoder
    for (int t = 0; t < TT - 1; t++) {
        dec_gates<<<dim3(4 * DH / 64), 256, 0, stream>>>(
            trg_emb, trg_tokens, av_bf, hc_bf, w_dWih, w_dWhh, dec_b, gates, t);
        dec_cell_attn<<<B, 256, 0, stream>>>(gates, dec_c, hc_bf, Henc, src_lens);
        gemm_bt<<<dim3(DH / 64), 256, 0, stream>>>(hc_bf, w_hid, hid_b, 2 * DH,
                                                   nullptr, 0, av_bf, DH, 0);
        out_gemm_loss<<<dim3(VT / 64), 256, 0, stream>>>(
            av_bf, w_out, out_b, trg_tokens, pm, ps, gval, t);
        combine_loss<<<B, 256, 0, stream>>>(pm, ps, gval, trg_lens, nll_buf, t);
    }

    write_out<<<1, 256, 0, stream>>>(nll_buf, (float*)d_out);
}

// Round 3
// 7874.732 us; speedup vs baseline: 3.0860x; 1.3337x over previous
//
#include <hip/hip_runtime.h>
#include <math.h>

#define B   64
#define TS  64
#define TT  64
#define E   512
#define H   512
#define DH  1024
#define VT  32000
#define MROWS ((TT - 1) * B)      // 4032 batched rows for av/out/loss
#define PARTS 512                 // stride for loss partials (500 used)

typedef __attribute__((ext_vector_type(8))) short short8;
typedef __attribute__((ext_vector_type(4))) float floatx4;

__device__ __forceinline__ ushort f2bf(float f) {
    union { float f; unsigned int i; } v; v.f = f;
    unsigned int u = v.i;
    return (ushort)((u + 0x7fffu + ((u >> 16) & 1u)) >> 16);
}
__device__ __forceinline__ float bf2f(ushort u) {
    union { unsigned int i; float f; } v; v.i = ((unsigned int)u) << 16;
    return v.f;
}
__device__ __forceinline__ short8 ld8h(const ushort* p) {
    return *(const short8*)p;
}
__device__ __forceinline__ float sigm(float x) { return 1.0f / (1.0f + expf(-x)); }

// ---------------------------------------------------------------------------
// one-time f32 -> bf16 tensor conversion (vectorized, grid-stride)
// ---------------------------------------------------------------------------
__global__ void conv_bf16(const float* __restrict__ src, ushort* __restrict__ dst, int n4)
{
    int i = blockIdx.x * 256 + threadIdx.x;
    int stride = gridDim.x * 256;
    for (; i < n4; i += stride) {
        float4 v = ((const float4*)src)[i];
        ushort4 o;
        o.x = f2bf(v.x); o.y = f2bf(v.y); o.z = f2bf(v.z); o.w = f2bf(v.w);
        ((ushort4*)dst)[i] = o;
    }
}

// transpose hid_W f32 [1024][2048] -> bf16 [2048][1024]
__global__ __launch_bounds__(256) void transp_hid(const float* __restrict__ src,
                                                  ushort* __restrict__ dst)
{
    __shared__ float t[64][65];
    int i0 = blockIdx.x * 64;            // dst row base (src col)
    int j0 = blockIdx.y * 64;            // src row base
    int c = threadIdx.x & 63, rr = threadIdx.x >> 6;
#pragma unroll
    for (int p = 0; p < 16; p++) {
        int r = rr + p * 4;
        t[r][c] = src[(size_t)(j0 + r) * 2048 + i0 + c];
    }
    __syncthreads();
#pragma unroll
    for (int p = 0; p < 16; p++) {
        int r = rr + p * 4;
        dst[(size_t)(i0 + r) * 1024 + j0 + c] = f2bf(t[c][r]);
    }
}

// copy We = dec_Wih[:, :512] (bf16) into Wpack[:, :512] (row stride 2560)
__global__ void copy_we(const ushort* __restrict__ src, ushort* __restrict__ dst)
{
    int idx = blockIdx.x * 256 + threadIdx.x;          // 4096 * 128 ushort4
    int stride = gridDim.x * 256;
    for (; idx < 4096 * 128; idx += stride) {
        int m = idx >> 7, k4 = idx & 127;
        ((ushort4*)(dst + (size_t)m * 2560))[k4] =
            ((const ushort4*)(src + (size_t)m * 1536))[k4];
    }
}

// bias2[m] = dec_b[m] + sum_j hid_b[j] * dec_Wih[m][512+j]   (f32, exactish)
__global__ __launch_bounds__(256) void fold_bias(const float* __restrict__ dec_Wih,
                                                 const float* __restrict__ dec_b,
                                                 const float* __restrict__ hid_b,
                                                 float* __restrict__ bias2)
{
    int wave = threadIdx.x >> 6, lane = threadIdx.x & 63;
    int row = blockIdx.x * 4 + wave;
    float s = 0.f;
    for (int k = 0; k < 16; k++) {
        int j = lane + k * 64;
        s += hid_b[j] * dec_Wih[(size_t)row * 1536 + 512 + j];
    }
    for (int off = 32; off >= 1; off >>= 1) s += __shfl_xor(s, off);
    if (lane == 0) bias2[row] = dec_b[row] + s;
}

// ---------------------------------------------------------------------------
// General 2D-grid GEMM: C[m][n] = sum_k A[m*lda+k] * W[n*ldw+k]  (bf16 MFMA).
// grid = (N/64, M/64), block 256 = 4 waves (2x2), wave tile 32x32.
// optional: bias[n], bf16 add source (col<addN), f32 out, bf16 out (opt tanh).
// MFMA layouts (HW-verified m89): A/B frag row=lane&15, k=(lane>>4)*8+j;
// C/D row=(lane>>4)*4+r, col=lane&15.
// ---------------------------------------------------------------------------
__global__ __launch_bounds__(256) void gemm_big(
    const ushort* __restrict__ A, int lda,
    const ushort* __restrict__ W, int ldw, int K,
    const float* __restrict__ bias,
    float* __restrict__ outf, int ldof,
    ushort* __restrict__ outb, int ldob, int do_tanh,
    const ushort* __restrict__ addp, int ldadd, int addN)
{
    const int tid  = threadIdx.x;
    const int wave = tid >> 6;
    const int lane = tid & 63;
    const int wm = wave >> 1, wn = wave & 1;
    const int l15 = lane & 15, quad = lane >> 4;
    const int m0 = blockIdx.y * 64 + wm * 32;
    const int n0 = blockIdx.x * 64 + wn * 32;
    const int koff = quad * 8;

    floatx4 acc[2][2] = {};
    const ushort* Ap0 = A + (size_t)(m0 + l15) * lda + koff;
    const ushort* Ap1 = Ap0 + (size_t)16 * lda;
    const ushort* Wp0 = W + (size_t)(n0 + l15) * ldw + koff;
    const ushort* Wp1 = Wp0 + (size_t)16 * ldw;
#pragma unroll 2
    for (int kb = 0; kb < K; kb += 32) {
        short8 a0 = ld8h(Ap0 + kb);
        short8 a1 = ld8h(Ap1 + kb);
        short8 w0 = ld8h(Wp0 + kb);
        short8 w1 = ld8h(Wp1 + kb);
        acc[0][0] = __builtin_amdgcn_mfma_f32_16x16x32_bf16(a0, w0, acc[0][0], 0, 0, 0);
        acc[0][1] = __builtin_amdgcn_mfma_f32_16x16x32_bf16(a0, w1, acc[0][1], 0, 0, 0);
        acc[1][0] = __builtin_amdgcn_mfma_f32_16x16x32_bf16(a1, w0, acc[1][0], 0, 0, 0);
        acc[1][1] = __builtin_amdgcn_mfma_f32_16x16x32_bf16(a1, w1, acc[1][1], 0, 0, 0);
    }
    for (int i = 0; i < 2; i++)
        for (int j = 0; j < 2; j++) {
            int col = n0 + j * 16 + l15;
            float bv = bias ? bias[col] : 0.0f;
            for (int r = 0; r < 4; r++) {
                int row = m0 + i * 16 + quad * 4 + r;
                float v = acc[i][j][r] + bv;
                if (addp && col < addN) v += bf2f(addp[(size_t)row * ldadd + col]);
                if (outf) outf[(size_t)row * ldof + col] = v;
                if (outb) outb[(size_t)row * ldob + col] = f2bf(do_tanh ? tanhf(v) : v);
            }
        }
}

// ---------------------------------------------------------------------------
// Encoder step, both directions: gates = sv[t] @ Wih^T + h_prev @ Whh^T + b,
// then LSTM cell. Grid: 64 blocks (dir = bid>>5, jt = bid&31).
// ---------------------------------------------------------------------------
__global__ __launch_bounds__(256) void enc_step(
    const ushort* __restrict__ Wih_f, const ushort* __restrict__ Whh_f,
    const float* __restrict__ bias_f,
    const ushort* __restrict__ Wih_r, const ushort* __restrict__ Whh_r,
    const float* __restrict__ bias_r,
    const ushort* __restrict__ sv,                       // [TS][B][E] bf16
    const ushort* __restrict__ hprev, ushort* __restrict__ hnext,  // [dir][B][H] bf16
    const float* __restrict__ cprev, float* __restrict__ cnext,
    float* __restrict__ Henc, ushort* __restrict__ final_bf,
    const int* __restrict__ src_lens, int t)
{
    const int d  = blockIdx.x >> 5;
    const int jt = blockIdx.x & 31;
    const int tid = threadIdx.x;
    const int wave = tid >> 6, lane = tid & 63;
    const int l15 = lane & 15, quad = lane >> 4;
    const ushort* Wih  = d ? Wih_r : Wih_f;
    const ushort* Whh  = d ? Whh_r : Whh_f;
    const float*  bias = d ? bias_r : bias_f;
    const ushort* hp = hprev + (size_t)d * (B * H);
    const int n0 = wave * H + jt * 16;      // column in 4H gate space
    const int koff = quad * 8;

    floatx4 acc[4] = {};
    const ushort* Wp = Wih + (size_t)(n0 + l15) * E + koff;
    const ushort* Ap = sv + (size_t)t * B * E + koff;
#pragma unroll 2
    for (int kb = 0; kb < E; kb += 32) {
        short8 w = ld8h(Wp + kb);
#pragma unroll
        for (int mi = 0; mi < 4; mi++) {
            short8 a = ld8h(Ap + (size_t)(mi * 16 + l15) * E + kb);
            acc[mi] = __builtin_amdgcn_mfma_f32_16x16x32_bf16(a, w, acc[mi], 0, 0, 0);
        }
    }
    const ushort* Wp2 = Whh + (size_t)(n0 + l15) * H + koff;
#pragma unroll 2
    for (int kb = 0; kb < H; kb += 32) {
        short8 w = ld8h(Wp2 + kb);
#pragma unroll
        for (int mi = 0; mi < 4; mi++) {
            short8 a = ld8h(hp + (size_t)(mi * 16 + l15) * H + kb + koff);
            acc[mi] = __builtin_amdgcn_mfma_f32_16x16x32_bf16(a, w, acc[mi], 0, 0, 0);
        }
    }

    __shared__ float gl[4][B][16];
    float bv = bias[n0 + l15];
    for (int mi = 0; mi < 4; mi++)
        for (int r = 0; r < 4; r++) {
            int b_ = mi * 16 + quad * 4 + r;
            gl[wave][b_][l15] = acc[mi][r] + bv;
        }
    __syncthreads();

    for (int p = tid; p < B * 16; p += 256) {
        int b_ = p >> 4, jl = p & 15;
        int j = jt * 16 + jl;
        float gi = gl[0][b_][jl], gf = gl[1][b_][jl];
        float gg = gl[2][b_][jl], go = gl[3][b_][jl];
        float cp = cprev[((size_t)d * B + b_) * H + j];
        float cn = sigm(gf) * cp + sigm(gi) * tanhf(gg);
        float hn = sigm(go) * tanhf(cn);
        cnext[((size_t)d * B + b_) * H + j] = cn;
        hnext[((size_t)d * B + b_) * H + j] = f2bf(hn);
        Henc[(size_t)(b_ * TS + t) * DH + d * H + j] = hn;
        if (t == src_lens[b_] - 1) {
            final_bf[b_ * (4 * H) + d * H + j] = f2bf(hn);           // H part
            final_bf[b_ * (4 * H) + 2 * H + d * H + j] = f2bf(cn);   // C part
        }
    }
}

// ---------------------------------------------------------------------------
// Decoder gates GEMM (folded): gates = A1(emb)@Wpack[:, :512]^T
//                                     + A2 @ W2^T + bias.
// t==0: A2 = h0_bf (K2=1024, W2=Whh, bias=dec_b)
// t>=1: A2 = hc_all[t-1] (K2=2048, W2=Wpack+512 [Wv@hid_W + [Whh|0]], bias=bias2)
// Grid 64 blocks over N=4096, M=64.
// ---------------------------------------------------------------------------
__global__ __launch_bounds__(256) void dec_gates2(
    const ushort* __restrict__ A1,       // tv_bf + t*B*E   [B][E]
    const ushort* __restrict__ Wpack,    // [4096][2560]
    const ushort* __restrict__ A2, int lda2,
    const ushort* __restrict__ W2, int ldw2, int K2,
    const float* __restrict__ bias, float* __restrict__ gates)
{
    const int tid = threadIdx.x;
    const int wave = tid >> 6, lane = tid & 63;
    const int wm = wave >> 1, wn = wave & 1;
    const int l15 = lane & 15, quad = lane >> 4;
    const int m0 = wm * 32;
    const int n0 = blockIdx.x * 64 + wn * 32;
    const int koff = quad * 8;

    floatx4 acc[2][2] = {};
    // segment 1: embedding, K=512
    {
        const ushort* a0p = A1 + (size_t)(m0 + l15) * E + koff;
        const ushort* a1p = a0p + (size_t)16 * E;
        const ushort* w0p = Wpack + (size_t)(n0 + l15) * 2560 + koff;
        const ushort* w1p = w0p + (size_t)16 * 2560;
#pragma unroll 2
        for (int kb = 0; kb < E; kb += 32) {
            short8 a0 = ld8h(a0p + kb);
            short8 a1 = ld8h(a1p + kb);
            short8 w0 = ld8h(w0p + kb);
            short8 w1 = ld8h(w1p + kb);
            acc[0][0] = __builtin_amdgcn_mfma_f32_16x16x32_bf16(a0, w0, acc[0][0], 0, 0, 0);
            acc[0][1] = __builtin_amdgcn_mfma_f32_16x16x32_bf16(a0, w1, acc[0][1], 0, 0, 0);
            acc[1][0] = __builtin_amdgcn_mfma_f32_16x16x32_bf16(a1, w0, acc[1][0], 0, 0, 0);
            acc[1][1] = __builtin_amdgcn_mfma_f32_16x16x32_bf16(a1, w1, acc[1][1], 0, 0, 0);
        }
    }
    // segment 2
    {
        const ushort* a0p = A2 + (size_t)(m0 + l15) * lda2 + koff;
        const ushort* a1p = a0p + (size_t)16 * lda2;
        const ushort* w0p = W2 + (size_t)(n0 + l15) * ldw2 + koff;
        const ushort* w1p = w0p + (size_t)16 * ldw2;
#pragma unroll 2
        for (int kb = 0; kb < K2; kb += 32) {
            short8 a0 = ld8h(a0p + kb);
            short8 a1 = ld8h(a1p + kb);
            short8 w0 = ld8h(w0p + kb);
            short8 w1 = ld8h(w1p + kb);
            acc[0][0] = __builtin_amdgcn_mfma_f32_16x16x32_bf16(a0, w0, acc[0][0], 0, 0, 0);
            acc[0][1] = __builtin_amdgcn_mfma_f32_16x16x32_bf16(a0, w1, acc[0][1], 0, 0, 0);
            acc[1][0] = __builtin_amdgcn_mfma_f32_16x16x32_bf16(a1, w0, acc[1][0], 0, 0, 0);
            acc[1][1] = __builtin_amdgcn_mfma_f32_16x16x32_bf16(a1, w1, acc[1][1], 0, 0, 0);
        }
    }

    for (int i = 0; i < 2; i++)
        for (int j = 0; j < 2; j++) {
            int col = n0 + j * 16 + l15;
            float bv = bias[col];
            for (int r = 0; r < 4; r++) {
                int row = m0 + i * 16 + quad * 4 + r;
                gates[(size_t)row * (4 * DH) + col] = acc[i][j][r] + bv;
            }
        }
}

// ---------------------------------------------------------------------------
// embed tokens -> bf16 [T][B][E] (time-major for contiguous A rows)
// ---------------------------------------------------------------------------
__global__ void embed_tm(const int* __restrict__ toks, const float* __restrict__ emb,
                         ushort* __restrict__ out)
{
    int bt = blockIdx.x;                 // b*64 + t
    int b_ = bt >> 6, t = bt & 63;
    int tok = toks[bt];
    const float* src = emb + (size_t)tok * E;
    ushort* dst = out + ((size_t)t * B + b_) * E;
    for (int e = threadIdx.x; e < E; e += 256) dst[e] = f2bf(src[e]);
}

// ---------------------------------------------------------------------------
// Fused decoder cell + attention. One block per batch row.
// Writes hc_all[t][b] = [h | ctx] (bf16).
// ---------------------------------------------------------------------------
__global__ __launch_bounds__(256) void dec_cell_attn(
    const float* __restrict__ gates, float* __restrict__ c,
    ushort* __restrict__ hc_out,                         // hc_all + t*B*2DH
    const float* __restrict__ Henc, const int* __restrict__ src_lens)
{
    int b_ = blockIdx.x, tid = threadIdx.x;
    __shared__ float hsm[DH];
    __shared__ float red[256];
    __shared__ float attn[TS];
    const float* g = gates + (size_t)b_ * 4 * DH;
    for (int j = tid; j < DH; j += 256) {
        float cn = sigm(g[DH + j]) * c[(size_t)b_ * DH + j]
                 + sigm(g[j]) * tanhf(g[2 * DH + j]);
        c[(size_t)b_ * DH + j] = cn;
        float hn = sigm(g[3 * DH + j]) * tanhf(cn);
        hsm[j] = hn;
        hc_out[(size_t)b_ * 2 * DH + j] = f2bf(hn);
    }
    __syncthreads();
    // scores[t] = h . Henc[b,t,:]
    int tq = tid & 63, part = tid >> 6;
    const float4* He4 = (const float4*)(Henc + (size_t)(b_ * TS + tq) * DH + part * 256);
    const float4* h4  = (const float4*)(hsm + part * 256);
    float pp = 0.f;
#pragma unroll 8
    for (int j = 0; j < 64; j++) {
        float4 a = He4[j]; float4 hh = h4[j];
        pp += a.x * hh.x + a.y * hh.y + a.z * hh.z + a.w * hh.w;
    }
    red[tid] = pp;
    __syncthreads();
    if (tid < 64) {
        float s = red[tid] + red[tid + 64] + red[tid + 128] + red[tid + 192];
        if (tid >= src_lens[b_]) s = -1e9f;
        float m = s;
        for (int off = 32; off >= 1; off >>= 1) m = fmaxf(m, __shfl_xor(m, off));
        float e = expf(s - m);
        float sum = e;
        for (int off = 32; off >= 1; off >>= 1) sum += __shfl_xor(sum, off);
        attn[tid] = e / sum;
    }
    __syncthreads();
    // ctx[j] = sum_t attn[t] * Henc[b,t,j]
    for (int k = 0; k < 4; k++) {
        int j = k * 256 + tid;
        float a = 0.f;
#pragma unroll 8
        for (int t2 = 0; t2 < TS; t2++)
            a += attn[t2] * Henc[(size_t)(b_ * TS + t2) * DH + j];
        hc_out[(size_t)b_ * 2 * DH + DH + j] = f2bf(a);
    }
}

// ---------------------------------------------------------------------------
// BATCHED output projection + loss partials over all (t,b) rows at once.
// Grid (63, 500): x = m-tile (t), y = n-tile -> consecutive blocks share W-tile.
// Per block: one part per row (two col-wave halves merged in LDS).
// ---------------------------------------------------------------------------
__global__ __launch_bounds__(256) void out_loss_b(
    const ushort* __restrict__ A,        // av_out [MROWS][DH] bf16
    const ushort* __restrict__ W,        // out_W bf16 [VT][DH]
    const float* __restrict__ bias,
    const int* __restrict__ trg_tokens,
    float* __restrict__ pm, float* __restrict__ ps, float* __restrict__ gval)
{
    const int tid = threadIdx.x;
    const int wave = tid >> 6, lane = tid & 63;
    const int wm = wave >> 1, wn = wave & 1;
    const int l15 = lane & 15, quad = lane >> 4;
    const int mt = blockIdx.x, nt = blockIdx.y;
    const int m0 = mt * 64 + wm * 32;
    const int n0 = nt * 64 + wn * 32;
    const int koff = quad * 8;

    __shared__ int gsm[B];
    __shared__ float lm[2][64], ls[2][64];
    if (tid < B) gsm[tid] = trg_tokens[tid * TT + mt + 1];

    floatx4 acc[2][2] = {};
    const ushort* Ap0 = A + (size_t)(m0 + l15) * DH + koff;
    const ushort* Ap1 = Ap0 + (size_t)16 * DH;
    const ushort* Wp0 = W + (size_t)(n0 + l15) * DH + koff;
    const ushort* Wp1 = Wp0 + (size_t)16 * DH;
#pragma unroll 2
    for (int kb = 0; kb < DH; kb += 32) {
        short8 a0 = ld8h(Ap0 + kb);
        short8 a1 = ld8h(Ap1 + kb);
        short8 w0 = ld8h(Wp0 + kb);
        short8 w1 = ld8h(Wp1 + kb);
        acc[0][0] = __builtin_amdgcn_mfma_f32_16x16x32_bf16(a0, w0, acc[0][0], 0, 0, 0);
        acc[0][1] = __builtin_amdgcn_mfma_f32_16x16x32_bf16(a0, w1, acc[0][1], 0, 0, 0);
        acc[1][0] = __builtin_amdgcn_mfma_f32_16x16x32_bf16(a1, w0, acc[1][0], 0, 0, 0);
        acc[1][1] = __builtin_amdgcn_mfma_f32_16x16x32_bf16(a1, w1, acc[1][1], 0, 0, 0);
    }
    __syncthreads();   // gsm visible

    for (int i = 0; i < 2; i++) {
        float v[2][4];
        for (int j = 0; j < 2; j++) {
            int col = n0 + j * 16 + l15;
            float bv = bias[col];
            for (int r = 0; r < 4; r++) {
                v[j][r] = acc[i][j][r] + bv;
                int lr = wm * 32 + i * 16 + quad * 4 + r;
                if (col == gsm[lr]) gval[mt * 64 + lr] = v[j][r];
            }
        }
        for (int r = 0; r < 4; r++) {
            float m = fmaxf(v[0][r], v[1][r]);
#pragma unroll
            for (int off = 1; off < 16; off <<= 1) m = fmaxf(m, __shfl_xor(m, off));
            float s = expf(v[0][r] - m) + expf(v[1][r] - m);
#pragma unroll
            for (int off = 1; off < 16; off <<= 1) s += __shfl_xor(s, off);
            if (l15 == 0) {
                int lr = wm * 32 + i * 16 + quad * 4 + r;
                lm[wn][lr] = m; ls[wn][lr] = s;
            }
        }
    }
    __syncthreads();
    if (tid < 64) {
        float m0v = lm[0][tid], m1v = lm[1][tid];
        float M = fmaxf(m0v, m1v);
        float S = ls[0][tid] * expf(m0v - M) + ls[1][tid] * expf(m1v - M);
        size_t rg = (size_t)(mt * 64 + tid);
        pm[rg * PARTS + nt] = M;
        ps[rg * PARTS + nt] = S;
    }
}

// Combine 500 partials per row -> lse -> masked lsm value. Grid MROWS blocks.
__global__ __launch_bounds__(256) void combine_loss(
    const float* __restrict__ pm, const float* __restrict__ ps,
    const float* __restrict__ gval, const int* __restrict__ trg_lens,
    float* __restrict__ nll_buf)
{
    int r = blockIdx.x, tid = threadIdx.x;
    int t = r >> 6, b_ = r & 63;
    __shared__ float red[256];
    const float* pmr = pm + (size_t)r * PARTS;
    const float* psr = ps + (size_t)r * PARTS;
    float m = -1e30f;
    for (int p = tid; p < 500; p += 256) m = fmaxf(m, pmr[p]);
    red[tid] = m; __syncthreads();
    for (int s = 128; s >= 1; s >>= 1) {
        if (tid < s) red[tid] = fmaxf(red[tid], red[tid + s]);
        __syncthreads();
    }
    m = red[0]; __syncthreads();
    float s = 0.f;
    for (int p = tid; p < 500; p += 256) s += psr[p] * expf(pmr[p] - m);
    red[tid] = s; __syncthreads();
    for (int st = 128; st >= 1; st >>= 1) {
        if (tid < st) red[tid] += red[tid + st];
        __syncthreads();
    }
    if (tid == 0) {
        float lse = m + logf(red[0]);
        nll_buf[r] = (t + 1 < trg_lens[b_]) ? (gval[r] - lse) : 0.f;
    }
}

__global__ void init_zero(ushort* hbf, float* cbuf)
{
    int idx = blockIdx.x * 256 + threadIdx.x;   // 131072 = 2*2*B*H
    hbf[idx] = 0;
    cbuf[idx] = 0.f;
}

__global__ __launch_bounds__(256) void write_out(const float* __restrict__ nll_buf,
                                                 float* __restrict__ out)
{
    __shared__ float red[256];
    float s = 0.f;
    for (int i = threadIdx.x; i < MROWS; i += 256) s += nll_buf[i];
    red[threadIdx.x] = s; __syncthreads();
    for (int st = 128; st >= 1; st >>= 1) {
        if (threadIdx.x < st) red[threadIdx.x] += red[threadIdx.x + st];
        __syncthreads();
    }
    if (threadIdx.x == 0) out[0] = red[0];
}

// ---------------------------------------------------------------------------
extern "C" void kernel_launch(void* const* d_in, const int* in_sizes, int n_in,
                              void* d_out, int out_size, void* d_ws, size_t ws_size,
                              hipStream_t stream)
{
    const int*   src_tokens = (const int*)d_in[0];
    const int*   src_lens   = (const int*)d_in[1];
    const int*   trg_tokens = (const int*)d_in[2];
    const int*   trg_lens   = (const int*)d_in[3];
    const float* src_emb    = (const float*)d_in[4];
    const float* trg_emb    = (const float*)d_in[5];
    const float* enc_Wih    = (const float*)d_in[6];
    const float* enc_Whh    = (const float*)d_in[7];
    const float* enc_b      = (const float*)d_in[8];
    const float* rev_Wih    = (const float*)d_in[9];
    const float* rev_Whh    = (const float*)d_in[10];
    const float* rev_b      = (const float*)d_in[11];
    const float* dec_Wih    = (const float*)d_in[12];
    const float* dec_Whh    = (const float*)d_in[13];
    const float* dec_b      = (const float*)d_in[14];
    const float* hid_W      = (const float*)d_in[15];
    const float* hid_b      = (const float*)d_in[16];
    const float* out_W      = (const float*)d_in[17];
    const float* out_b      = (const float*)d_in[18];
    const float* init_W     = (const float*)d_in[19];
    const float* init_b     = (const float*)d_in[20];

    char* ws = (char*)d_ws;
    size_t off = 0;
    auto alloc = [&](size_t bytes) -> void* {
        void* p = ws + off;
        off = (off + bytes + 255) & ~(size_t)255;
        return p;
    };
    // activations / state
    ushort* sv_bf    = (ushort*)alloc((size_t)TS * B * E * 2);        // 4.2 MB
    ushort* tv_bf    = (ushort*)alloc((size_t)TT * B * E * 2);        // 4.2 MB
    float*  Henc     = (float*) alloc((size_t)B * TS * DH * 4);       // 16.8 MB
    ushort* hbf      = (ushort*)alloc((size_t)2 * 2 * B * H * 2);     // enc ping-pong
    float*  cbuf     = (float*) alloc((size_t)2 * 2 * B * H * 4);
    ushort* final_bf = (ushort*)alloc((size_t)B * 4 * H * 2);
    float*  gates    = (float*) alloc((size_t)B * 4 * DH * 4);        // 1 MB
    float*  dec_c    = (float*) alloc((size_t)B * DH * 4);
    ushort* h0_bf    = (ushort*)alloc((size_t)B * DH * 2);
    ushort* hc_all   = (ushort*)alloc((size_t)(TT - 1) * B * 2 * DH * 2); // 16.5 MB
    ushort* av_out   = (ushort*)alloc((size_t)MROWS * DH * 2);        // 8.3 MB
    float*  pm       = (float*) alloc((size_t)MROWS * PARTS * 4);     // 8.3 MB
    float*  ps       = (float*) alloc((size_t)MROWS * PARTS * 4);     // 8.3 MB
    float*  gval     = (float*) alloc((size_t)MROWS * 4);
    float*  nll_buf  = (float*) alloc((size_t)MROWS * 4);
    float*  bias2    = (float*) alloc((size_t)4 * DH * 4);
    // bf16 weights
    ushort* w_eWih_f = (ushort*)alloc((size_t)4 * H * E * 2);
    ushort* w_eWhh_f = (ushort*)alloc((size_t)4 * H * H * 2);
    ushort* w_eWih_r = (ushort*)alloc((size_t)4 * H * E * 2);
    ushort* w_eWhh_r = (ushort*)alloc((size_t)4 * H * H * 2);
    ushort* w_dWih   = (ushort*)alloc((size_t)4 * DH * 1536 * 2);     // 12.6 MB
    ushort* w_dWhh   = (ushort*)alloc((size_t)4 * DH * DH * 2);       // 8.4 MB
    ushort* w_hid    = (ushort*)alloc((size_t)DH * 2 * DH * 2);       // 4 MB
    ushort* w_out    = (ushort*)alloc((size_t)VT * DH * 2);           // 65.5 MB
    ushort* w_init   = (ushort*)alloc((size_t)DH * 2 * DH * 2);       // 4 MB
    ushort* w_pack   = (ushort*)alloc((size_t)4 * DH * 2560 * 2);     // 21 MB
    // transient: hid_W^T (bf16) aliases pm (pm first used much later)
    ushort* hidWT    = (ushort*)pm;                                   // 4 MB < 8.3 MB

    // ---- one-time precompute ----
    conv_bf16<<<512, 256, 0, stream>>>(enc_Wih, w_eWih_f, 4 * H * E / 4);
    conv_bf16<<<512, 256, 0, stream>>>(enc_Whh, w_eWhh_f, 4 * H * H / 4);
    conv_bf16<<<512, 256, 0, stream>>>(rev_Wih, w_eWih_r, 4 * H * E / 4);
    conv_bf16<<<512, 256, 0, stream>>>(rev_Whh, w_eWhh_r, 4 * H * H / 4);
    conv_bf16<<<512, 256, 0, stream>>>(dec_Wih, w_dWih, 4 * DH * 1536 / 4);
    conv_bf16<<<512, 256, 0, stream>>>(dec_Whh, w_dWhh, 4 * DH * DH / 4);
    conv_bf16<<<512, 256, 0, stream>>>(hid_W, w_hid, DH * 2 * DH / 4);
    conv_bf16<<<2048, 256, 0, stream>>>(out_W, w_out, VT * DH / 4);
    conv_bf16<<<512, 256, 0, stream>>>(init_W, w_init, DH * 2 * DH / 4);

    // hid_W^T bf16
    transp_hid<<<dim3(32, 16), 256, 0, stream>>>(hid_W, hidWT);
    // Wmod = Wv @ hid_W + [Whh | 0]  ->  w_pack[:, 512:2560]
    gemm_big<<<dim3(32, 64), 256, 0, stream>>>(
        w_dWih + 512, 1536, hidWT, 1024, 1024,
        nullptr, nullptr, 0, w_pack + 512, 2560, 0,
        w_dWhh, 1024, 1024);
    // We -> w_pack[:, :512]
    copy_we<<<512, 256, 0, stream>>>(w_dWih, w_pack);
    // bias2 = dec_b + Wv @ hid_b
    fold_bias<<<1024, 256, 0, stream>>>(dec_Wih, dec_b, hid_b, bias2);

    init_zero<<<2 * 2 * B * H / 256, 256, 0, stream>>>(hbf, cbuf);
    embed_tm<<<B * TS, 256, 0, stream>>>(src_tokens, src_emb, sv_bf);
    embed_tm<<<B * TT, 256, 0, stream>>>(trg_tokens, trg_emb, tv_bf);

    // ---- encoder recurrence ----
    for (int t = 0; t < TS; t++) {
        int par = t & 1;
        enc_step<<<64, 256, 0, stream>>>(
            w_eWih_f, w_eWhh_f, enc_b, w_eWih_r, w_eWhh_r, rev_b, sv_bf,
            hbf + (size_t)par * 2 * B * H, hbf + (size_t)(par ^ 1) * 2 * B * H,
            cbuf + (size_t)par * 2 * B * H, cbuf + (size_t)(par ^ 1) * 2 * B * H,
            Henc, final_bf, src_lens, t);
    }

    // c0 (f32) and h0 = tanh(c0) (bf16)
    gemm_big<<<dim3(16, 1), 256, 0, stream>>>(
        final_bf, 2 * DH, w_init, 2 * DH, 2 * DH,
        init_b, dec_c, DH, h0_bf, DH, 1, nullptr, 0, 0);

    // ---- decoder recurrence (2 kernels per step) ----
    for (int t = 0; t < TT - 1; t++) {
        if (t == 0) {
            dec_gates2<<<64, 256, 0, stream>>>(
                tv_bf, w_pack, h0_bf, DH, w_dWhh, DH, DH, dec_b, gates);
        } else {
            dec_gates2<<<64, 256, 0, stream>>>(
                tv_bf + (size_t)t * B * E, w_pack,
                hc_all + (size_t)(t - 1) * B * 2 * DH, 2 * DH,
                w_pack + 512, 2560, 2 * DH, bias2, gates);
        }
        dec_cell_attn<<<B, 256, 0, stream>>>(
            gates, dec_c, hc_all + (size_t)t * B * 2 * DH, Henc, src_lens);
    }

    // ---- batched av projection: av_out[r] = hid(hc_all[r]) ----
    gemm_big<<<dim3(16, MROWS / 64), 256, 0, stream>>>(
        hc_all, 2 * DH, w_hid, 2 * DH, 2 * DH,
        hid_b, nullptr, 0, av_out, DH, 0, nullptr, 0, 0);

    // ---- batched output projection + fused loss partials ----
    out_loss_b<<<dim3(MROWS / 64, VT / 64), 256, 0, stream>>>(
        av_out, w_out, out_b, trg_tokens, pm, ps, gval);
    combine_loss<<<MROWS, 256, 0, stream>>>(pm, ps, gval, trg_lens, nll_buf);
    write_out<<<1, 256, 0, stream>>>(nll_buf, (float*)d_out);
}

// Round 4
// 4654.332 us; speedup vs baseline: 5.2212x; 1.6919x over previous
//
#include <hip/hip_runtime.h>
#include <math.h>

#define B   64
#define TS  64
#define TT  64
#define E   512
#define H   512
#define DH  1024
#define VT  32000
#define MROWS ((TT - 1) * B)      // 4032 batched rows for av/out/loss
#define PARTS 128                 // stride for loss partials (125 used)
#define XROW 2560                 // [emb(512) | h(1024) | ctx(1024)]

typedef __attribute__((ext_vector_type(8))) short short8;
typedef __attribute__((ext_vector_type(4))) float floatx4;

__device__ __forceinline__ ushort f2bf(float f) {
    union { float f; unsigned int i; } v; v.f = f;
    unsigned int u = v.i;
    return (ushort)((u + 0x7fffu + ((u >> 16) & 1u)) >> 16);
}
__device__ __forceinline__ float bf2f(ushort u) {
    union { unsigned int i; float f; } v; v.i = ((unsigned int)u) << 16;
    return v.f;
}
__device__ __forceinline__ short8 ld8h(const ushort* p) {
    return *(const short8*)p;
}
__device__ __forceinline__ float sigm(float x) { return 1.0f / (1.0f + expf(-x)); }

// ---------------------------------------------------------------------------
// one-time f32 -> bf16 tensor conversion (vectorized, grid-stride)
// ---------------------------------------------------------------------------
__global__ void conv_bf16(const float* __restrict__ src, ushort* __restrict__ dst, int n4)
{
    int i = blockIdx.x * 256 + threadIdx.x;
    int stride = gridDim.x * 256;
    for (; i < n4; i += stride) {
        float4 v = ((const float4*)src)[i];
        ushort4 o;
        o.x = f2bf(v.x); o.y = f2bf(v.y); o.z = f2bf(v.z); o.w = f2bf(v.w);
        ((ushort4*)dst)[i] = o;
    }
}

// transpose hid_W f32 [1024][2048] -> bf16 [2048][1024]
__global__ __launch_bounds__(256) void transp_hid(const float* __restrict__ src,
                                                  ushort* __restrict__ dst)
{
    __shared__ float t[64][65];
    int i0 = blockIdx.x * 64;            // dst row base (src col)
    int j0 = blockIdx.y * 64;            // src row base
    int c = threadIdx.x & 63, rr = threadIdx.x >> 6;
#pragma unroll
    for (int p = 0; p < 16; p++) {
        int r = rr + p * 4;
        t[r][c] = src[(size_t)(j0 + r) * 2048 + i0 + c];
    }
    __syncthreads();
#pragma unroll
    for (int p = 0; p < 16; p++) {
        int r = rr + p * 4;
        dst[(size_t)(i0 + r) * 1024 + j0 + c] = f2bf(t[c][r]);
    }
}

// copy We = dec_Wih[:, :512] (bf16) into Wpack[:, :512] (row stride 2560)
__global__ void copy_we(const ushort* __restrict__ src, ushort* __restrict__ dst)
{
    int idx = blockIdx.x * 256 + threadIdx.x;          // 4096 * 128 ushort4
    int stride = gridDim.x * 256;
    for (; idx < 4096 * 128; idx += stride) {
        int m = idx >> 7, k4 = idx & 127;
        ((ushort4*)(dst + (size_t)m * XROW))[k4] =
            ((const ushort4*)(src + (size_t)m * 1536))[k4];
    }
}

// bias2[m] = dec_b[m] + sum_j hid_b[j] * dec_Wih[m][512+j]
__global__ __launch_bounds__(256) void fold_bias(const float* __restrict__ dec_Wih,
                                                 const float* __restrict__ dec_b,
                                                 const float* __restrict__ hid_b,
                                                 float* __restrict__ bias2)
{
    int wave = threadIdx.x >> 6, lane = threadIdx.x & 63;
    int row = blockIdx.x * 4 + wave;
    float s = 0.f;
    for (int k = 0; k < 16; k++) {
        int j = lane + k * 64;
        s += hid_b[j] * dec_Wih[(size_t)row * 1536 + 512 + j];
    }
    for (int off = 32; off >= 1; off >>= 1) s += __shfl_xor(s, off);
    if (lane == 0) bias2[row] = dec_b[row] + s;
}

// ---------------------------------------------------------------------------
// General 2D-grid GEMM: C[m][n] = sum_k A[m*lda+k] * W[n*ldw+k]  (bf16 MFMA).
// grid = (N/64, M/64), block 256 = 4 waves (2x2), wave tile 32x32.
// MFMA layouts (HW-verified m89): A/B frag row=lane&15, k=(lane>>4)*8+j;
// C/D row=(lane>>4)*4+r, col=lane&15.
// ---------------------------------------------------------------------------
__global__ __launch_bounds__(256) void gemm_big(
    const ushort* __restrict__ A, int lda,
    const ushort* __restrict__ W, int ldw, int K,
    const float* __restrict__ bias,
    float* __restrict__ outf, int ldof,
    ushort* __restrict__ outb, int ldob, int do_tanh,
    const ushort* __restrict__ addp, int ldadd, int addN)
{
    const int tid  = threadIdx.x;
    const int wave = tid >> 6;
    const int lane = tid & 63;
    const int wm = wave >> 1, wn = wave & 1;
    const int l15 = lane & 15, quad = lane >> 4;
    const int m0 = blockIdx.y * 64 + wm * 32;
    const int n0 = blockIdx.x * 64 + wn * 32;
    const int koff = quad * 8;

    floatx4 acc[2][2] = {};
    const ushort* Ap0 = A + (size_t)(m0 + l15) * lda + koff;
    const ushort* Ap1 = Ap0 + (size_t)16 * lda;
    const ushort* Wp0 = W + (size_t)(n0 + l15) * ldw + koff;
    const ushort* Wp1 = Wp0 + (size_t)16 * ldw;
#pragma unroll 2
    for (int kb = 0; kb < K; kb += 32) {
        short8 a0 = ld8h(Ap0 + kb);
        short8 a1 = ld8h(Ap1 + kb);
        short8 w0 = ld8h(Wp0 + kb);
        short8 w1 = ld8h(Wp1 + kb);
        acc[0][0] = __builtin_amdgcn_mfma_f32_16x16x32_bf16(a0, w0, acc[0][0], 0, 0, 0);
        acc[0][1] = __builtin_amdgcn_mfma_f32_16x16x32_bf16(a0, w1, acc[0][1], 0, 0, 0);
        acc[1][0] = __builtin_amdgcn_mfma_f32_16x16x32_bf16(a1, w0, acc[1][0], 0, 0, 0);
        acc[1][1] = __builtin_amdgcn_mfma_f32_16x16x32_bf16(a1, w1, acc[1][1], 0, 0, 0);
    }
    for (int i = 0; i < 2; i++)
        for (int j = 0; j < 2; j++) {
            int col = n0 + j * 16 + l15;
            float bv = bias ? bias[col] : 0.0f;
            for (int r = 0; r < 4; r++) {
                int row = m0 + i * 16 + quad * 4 + r;
                float v = acc[i][j][r] + bv;
                if (addp && col < addN) v += bf2f(addp[(size_t)row * ldadd + col]);
                if (outf) outf[(size_t)row * ldof + col] = v;
                if (outb) outb[(size_t)row * ldob + col] = f2bf(do_tanh ? tanhf(v) : v);
            }
        }
}

// ---------------------------------------------------------------------------
// Encoder step, both directions: gates = sv[t] @ Wih^T + h_prev @ Whh^T + b,
// then LSTM cell. Grid: 64 blocks (dir = bid>>5, jt = bid&31).
// ---------------------------------------------------------------------------
__global__ __launch_bounds__(256) void enc_step(
    const ushort* __restrict__ Wih_f, const ushort* __restrict__ Whh_f,
    const float* __restrict__ bias_f,
    const ushort* __restrict__ Wih_r, const ushort* __restrict__ Whh_r,
    const float* __restrict__ bias_r,
    const ushort* __restrict__ sv,                       // [TS][B][E] bf16
    const ushort* __restrict__ hprev, ushort* __restrict__ hnext,  // [dir][B][H] bf16
    const float* __restrict__ cprev, float* __restrict__ cnext,
    ushort* __restrict__ Henc_bf, ushort* __restrict__ final_bf,
    const int* __restrict__ src_lens, int t)
{
    const int d  = blockIdx.x >> 5;
    const int jt = blockIdx.x & 31;
    const int tid = threadIdx.x;
    const int wave = tid >> 6, lane = tid & 63;
    const int l15 = lane & 15, quad = lane >> 4;
    const ushort* Wih  = d ? Wih_r : Wih_f;
    const ushort* Whh  = d ? Whh_r : Whh_f;
    const float*  bias = d ? bias_r : bias_f;
    const ushort* hp = hprev + (size_t)d * (B * H);
    const int n0 = wave * H + jt * 16;      // column in 4H gate space
    const int koff = quad * 8;

    floatx4 acc[4] = {};
    const ushort* Wp = Wih + (size_t)(n0 + l15) * E + koff;
    const ushort* Ap = sv + (size_t)t * B * E + koff;
#pragma unroll 2
    for (int kb = 0; kb < E; kb += 32) {
        short8 w = ld8h(Wp + kb);
#pragma unroll
        for (int mi = 0; mi < 4; mi++) {
            short8 a = ld8h(Ap + (size_t)(mi * 16 + l15) * E + kb);
            acc[mi] = __builtin_amdgcn_mfma_f32_16x16x32_bf16(a, w, acc[mi], 0, 0, 0);
        }
    }
    const ushort* Wp2 = Whh + (size_t)(n0 + l15) * H + koff;
#pragma unroll 2
    for (int kb = 0; kb < H; kb += 32) {
        short8 w = ld8h(Wp2 + kb);
#pragma unroll
        for (int mi = 0; mi < 4; mi++) {
            short8 a = ld8h(hp + (size_t)(mi * 16 + l15) * H + kb + koff);
            acc[mi] = __builtin_amdgcn_mfma_f32_16x16x32_bf16(a, w, acc[mi], 0, 0, 0);
        }
    }

    __shared__ float gl[4][B][16];
    float bv = bias[n0 + l15];
    for (int mi = 0; mi < 4; mi++)
        for (int r = 0; r < 4; r++) {
            int b_ = mi * 16 + quad * 4 + r;
            gl[wave][b_][l15] = acc[mi][r] + bv;
        }
    __syncthreads();

    for (int p = tid; p < B * 16; p += 256) {
        int b_ = p >> 4, jl = p & 15;
        int j = jt * 16 + jl;
        float gi = gl[0][b_][jl], gf = gl[1][b_][jl];
        float gg = gl[2][b_][jl], go = gl[3][b_][jl];
        float cp = cprev[((size_t)d * B + b_) * H + j];
        float cn = sigm(gf) * cp + sigm(gi) * tanhf(gg);
        float hn = sigm(go) * tanhf(cn);
        cnext[((size_t)d * B + b_) * H + j] = cn;
        hnext[((size_t)d * B + b_) * H + j] = f2bf(hn);
        Henc_bf[(size_t)(b_ * TS + t) * DH + d * H + j] = f2bf(hn);
        if (t == src_lens[b_] - 1) {
            final_bf[b_ * (4 * H) + d * H + j] = f2bf(hn);           // H part
            final_bf[b_ * (4 * H) + 2 * H + d * H + j] = f2bf(cn);   // C part
        }
    }
}

// ---------------------------------------------------------------------------
// Decoder gates t=0 (2 segments): gates = emb@We^T + h0@Whh^T + dec_b.
// Grid 64 blocks over N=4096, M=64. (One launch only; kept simple.)
// ---------------------------------------------------------------------------
__global__ __launch_bounds__(256) void dec_gates_t0(
    const ushort* __restrict__ A1, int lda1,   // xrow[0]: emb at offset 0
    const ushort* __restrict__ Wpack,          // [4096][XROW], We at offset 0
    const ushort* __restrict__ A2, int lda2,   // h0_bf
    const ushort* __restrict__ W2, int ldw2, int K2,
    const float* __restrict__ bias, float* __restrict__ gates)
{
    const int tid = threadIdx.x;
    const int wave = tid >> 6, lane = tid & 63;
    const int wm = wave >> 1, wn = wave & 1;
    const int l15 = lane & 15, quad = lane >> 4;
    const int m0 = wm * 32;
    const int n0 = blockIdx.x * 64 + wn * 32;
    const int koff = quad * 8;

    floatx4 acc[2][2] = {};
    {
        const ushort* a0p = A1 + (size_t)(m0 + l15) * lda1 + koff;
        const ushort* a1p = a0p + (size_t)16 * lda1;
        const ushort* w0p = Wpack + (size_t)(n0 + l15) * XROW + koff;
        const ushort* w1p = w0p + (size_t)16 * XROW;
#pragma unroll 2
        for (int kb = 0; kb < E; kb += 32) {
            short8 a0 = ld8h(a0p + kb);
            short8 a1 = ld8h(a1p + kb);
            short8 w0 = ld8h(w0p + kb);
            short8 w1 = ld8h(w1p + kb);
            acc[0][0] = __builtin_amdgcn_mfma_f32_16x16x32_bf16(a0, w0, acc[0][0], 0, 0, 0);
            acc[0][1] = __builtin_amdgcn_mfma_f32_16x16x32_bf16(a0, w1, acc[0][1], 0, 0, 0);
            acc[1][0] = __builtin_amdgcn_mfma_f32_16x16x32_bf16(a1, w0, acc[1][0], 0, 0, 0);
            acc[1][1] = __builtin_amdgcn_mfma_f32_16x16x32_bf16(a1, w1, acc[1][1], 0, 0, 0);
        }
    }
    {
        const ushort* a0p = A2 + (size_t)(m0 + l15) * lda2 + koff;
        const ushort* a1p = a0p + (size_t)16 * lda2;
        const ushort* w0p = W2 + (size_t)(n0 + l15) * ldw2 + koff;
        const ushort* w1p = w0p + (size_t)16 * ldw2;
#pragma unroll 2
        for (int kb = 0; kb < K2; kb += 32) {
            short8 a0 = ld8h(a0p + kb);
            short8 a1 = ld8h(a1p + kb);
            short8 w0 = ld8h(w0p + kb);
            short8 w1 = ld8h(w1p + kb);
            acc[0][0] = __builtin_amdgcn_mfma_f32_16x16x32_bf16(a0, w0, acc[0][0], 0, 0, 0);
            acc[0][1] = __builtin_amdgcn_mfma_f32_16x16x32_bf16(a0, w1, acc[0][1], 0, 0, 0);
            acc[1][0] = __builtin_amdgcn_mfma_f32_16x16x32_bf16(a1, w0, acc[1][0], 0, 0, 0);
            acc[1][1] = __builtin_amdgcn_mfma_f32_16x16x32_bf16(a1, w1, acc[1][1], 0, 0, 0);
        }
    }
    for (int i = 0; i < 2; i++)
        for (int j = 0; j < 2; j++) {
            int col = n0 + j * 16 + l15;
            float bv = bias[col];
            for (int r = 0; r < 4; r++) {
                int row = m0 + i * 16 + quad * 4 + r;
                gates[(size_t)row * (4 * DH) + col] = acc[i][j][r] + bv;
            }
        }
}

// ---------------------------------------------------------------------------
// Decoder gates t>=1: gates = xrow[t] @ Wpack^T + bias2.
// Grid 256 blocks (full CU coverage): block = 16 cols, 4 waves K-split (640).
// LDS reduce across waves + bias.
// ---------------------------------------------------------------------------
__global__ __launch_bounds__(256) void dec_gates3(
    const ushort* __restrict__ A,        // xrow[t]  [64][XROW]
    const ushort* __restrict__ W,        // w_pack   [4096][XROW]
    const float* __restrict__ bias2, float* __restrict__ gates)
{
    const int tid = threadIdx.x;
    const int wave = tid >> 6, lane = tid & 63;
    const int l15 = lane & 15, quad = lane >> 4;
    const int n0 = blockIdx.x * 16;
    const int k0 = wave * (XROW / 4);          // 640 per wave
    const int koff = quad * 8;

    floatx4 acc[4] = {};
    const ushort* Ap = A + (size_t)l15 * XROW + k0 + koff;
    const ushort* Wp = W + (size_t)(n0 + l15) * XROW + k0 + koff;
#pragma unroll 2
    for (int kb = 0; kb < XROW / 4; kb += 32) {
        short8 w = ld8h(Wp + kb);
#pragma unroll
        for (int mi = 0; mi < 4; mi++) {
            short8 a = ld8h(Ap + (size_t)mi * 16 * XROW + kb);
            acc[mi] = __builtin_amdgcn_mfma_f32_16x16x32_bf16(a, w, acc[mi], 0, 0, 0);
        }
    }
    __shared__ float part[4][B][17];
    for (int mi = 0; mi < 4; mi++)
        for (int r = 0; r < 4; r++)
            part[wave][mi * 16 + quad * 4 + r][l15] = acc[mi][r];
    __syncthreads();
    for (int p = tid; p < B * 16; p += 256) {
        int b_ = p >> 4, jl = p & 15;
        float v = part[0][b_][jl] + part[1][b_][jl] + part[2][b_][jl] + part[3][b_][jl]
                + bias2[n0 + jl];
        gates[(size_t)b_ * (4 * DH) + n0 + jl] = v;
    }
}

// ---------------------------------------------------------------------------
// embed src tokens -> sv_bf [TS][B][E]
// ---------------------------------------------------------------------------
__global__ void embed_src(const int* __restrict__ toks, const float* __restrict__ emb,
                          ushort* __restrict__ sv)
{
    int bt = blockIdx.x;                 // b*64 + t
    int b_ = bt >> 6, t = bt & 63;
    int tok = toks[bt];
    const float* src = emb + (size_t)tok * E;
    ushort* dst = sv + ((size_t)t * B + b_) * E;
    for (int e = threadIdx.x; e < E; e += 256) dst[e] = f2bf(src[e]);
}

// embed trg tokens -> xrow[t][b][0:512]
__global__ void embed_trg(const int* __restrict__ toks, const float* __restrict__ emb,
                          ushort* __restrict__ xrow)
{
    int bt = blockIdx.x;                 // b*64 + t
    int b_ = bt >> 6, t = bt & 63;
    int tok = toks[bt];
    const float* src = emb + (size_t)tok * E;
    ushort* dst = xrow + ((size_t)t * B + b_) * XROW;
    for (int e = threadIdx.x; e < E; e += 256) dst[e] = f2bf(src[e]);
}

// ---------------------------------------------------------------------------
// Fused decoder cell + attention (512 threads). One block per batch row.
// Writes h -> xnext[b][512:1536], ctx -> xnext[b][1536:2560]  (xnext = xrow[t+1]).
// ---------------------------------------------------------------------------
__global__ __launch_bounds__(512) void dec_cell_attn(
    const float* __restrict__ gates, float* __restrict__ c,
    ushort* __restrict__ xnext,
    const ushort* __restrict__ Henc_bf, const int* __restrict__ src_lens)
{
    int b_ = blockIdx.x, tid = threadIdx.x;
    __shared__ float hsm[DH];
    __shared__ float red[512];
    __shared__ float attn[TS];
    const float* g = gates + (size_t)b_ * 4 * DH;
    for (int j = tid; j < DH; j += 512) {
        float cn = sigm(g[DH + j]) * c[(size_t)b_ * DH + j]
                 + sigm(g[j]) * tanhf(g[2 * DH + j]);
        c[(size_t)b_ * DH + j] = cn;
        float hn = sigm(g[3 * DH + j]) * tanhf(cn);
        hsm[j] = hn;
        xnext[(size_t)b_ * XROW + 512 + j] = f2bf(hn);
    }
    __syncthreads();
    // scores[t] = h . Henc[b,t,:]  (8 partials of 128 each)
    int tq = tid & 63, part = tid >> 6;
    const ushort* He = Henc_bf + (size_t)(b_ * TS + tq) * DH + part * 128;
    const float* hh = hsm + part * 128;
    float pp = 0.f;
#pragma unroll
    for (int jj = 0; jj < 128; jj += 8) {
        short8 hv = ld8h(He + jj);
#pragma unroll
        for (int k = 0; k < 8; k++) pp += bf2f((ushort)hv[k]) * hh[jj + k];
    }
    red[tid] = pp;
    __syncthreads();
    if (tid < 64) {
        float s = 0.f;
#pragma unroll
        for (int p = 0; p < 8; p++) s += red[tid + p * 64];
        if (tid >= src_lens[b_]) s = -1e9f;
        float m = s;
        for (int off = 32; off >= 1; off >>= 1) m = fmaxf(m, __shfl_xor(m, off));
        float e = expf(s - m);
        float sum = e;
        for (int off = 32; off >= 1; off >>= 1) sum += __shfl_xor(sum, off);
        attn[tid] = e / sum;
    }
    __syncthreads();
    // ctx[j] = sum_t attn[t] * Henc[b,t,j]
#pragma unroll
    for (int k = 0; k < 2; k++) {
        int j = k * 512 + tid;
        float a = 0.f;
#pragma unroll 8
        for (int t2 = 0; t2 < TS; t2++)
            a += attn[t2] * bf2f(Henc_bf[(size_t)(b_ * TS + t2) * DH + j]);
        xnext[(size_t)b_ * XROW + 1536 + j] = f2bf(a);
    }
}

// ---------------------------------------------------------------------------
// BATCHED output projection + loss partials. Block tile 64x256, 4 waves along N,
// each wave 64x64 (4x4 fragments, 16 MFMA : 8 loads per K-step).
// Grid (63, 125), x = m-tile fastest -> W-tile (512 KB) L2-reused across 63 blocks.
// ---------------------------------------------------------------------------
__global__ __launch_bounds__(256) void out_loss_b(
    const ushort* __restrict__ A,        // av_out [MROWS][DH] bf16
    const ushort* __restrict__ W,        // out_W bf16 [VT][DH]
    const float* __restrict__ bias,
    const int* __restrict__ trg_tokens,
    float* __restrict__ pm, float* __restrict__ ps, float* __restrict__ gval)
{
    const int tid = threadIdx.x;
    const int wave = tid >> 6, lane = tid & 63;
    const int l15 = lane & 15, quad = lane >> 4;
    const int mt = blockIdx.x, nt = blockIdx.y;
    const int m0 = mt * 64;
    const int n0 = nt * 256 + wave * 64;
    const int koff = quad * 8;

    __shared__ int gsm[B];
    __shared__ float lm[4][64], ls[4][64];
    if (tid < B) gsm[tid] = trg_tokens[tid * TT + mt + 1];

    floatx4 acc[4][4] = {};                  // [mi][nj]
    const ushort* Ap = A + (size_t)(m0 + l15) * DH + koff;
    const ushort* Wp = W + (size_t)(n0 + l15) * DH + koff;
#pragma unroll 2
    for (int kb = 0; kb < DH; kb += 32) {
        short8 a[4], w[4];
#pragma unroll
        for (int mi = 0; mi < 4; mi++) a[mi] = ld8h(Ap + (size_t)mi * 16 * DH + kb);
#pragma unroll
        for (int nj = 0; nj < 4; nj++) w[nj] = ld8h(Wp + (size_t)nj * 16 * DH + kb);
#pragma unroll
        for (int mi = 0; mi < 4; mi++)
#pragma unroll
            for (int nj = 0; nj < 4; nj++)
                acc[mi][nj] = __builtin_amdgcn_mfma_f32_16x16x32_bf16(
                    a[mi], w[nj], acc[mi][nj], 0, 0, 0);
    }
    __syncthreads();   // gsm visible

    for (int mi = 0; mi < 4; mi++) {
        float v[4][4];
#pragma unroll
        for (int nj = 0; nj < 4; nj++) {
            int col = n0 + nj * 16 + l15;
            float bv = bias[col];
#pragma unroll
            for (int r = 0; r < 4; r++) {
                v[nj][r] = acc[mi][nj][r] + bv;
                int lr = mi * 16 + quad * 4 + r;
                if (col == gsm[lr]) gval[m0 + lr] = v[nj][r];
            }
        }
#pragma unroll
        for (int r = 0; r < 4; r++) {
            float mx = fmaxf(fmaxf(v[0][r], v[1][r]), fmaxf(v[2][r], v[3][r]));
#pragma unroll
            for (int off = 1; off < 16; off <<= 1) mx = fmaxf(mx, __shfl_xor(mx, off));
            float s = expf(v[0][r] - mx) + expf(v[1][r] - mx)
                    + expf(v[2][r] - mx) + expf(v[3][r] - mx);
#pragma unroll
            for (int off = 1; off < 16; off <<= 1) s += __shfl_xor(s, off);
            if (l15 == 0) {
                int lr = mi * 16 + quad * 4 + r;
                lm[wave][lr] = mx; ls[wave][lr] = s;
            }
        }
    }
    __syncthreads();
    if (tid < 64) {
        float M = fmaxf(fmaxf(lm[0][tid], lm[1][tid]), fmaxf(lm[2][tid], lm[3][tid]));
        float S = ls[0][tid] * expf(lm[0][tid] - M) + ls[1][tid] * expf(lm[1][tid] - M)
                + ls[2][tid] * expf(lm[2][tid] - M) + ls[3][tid] * expf(lm[3][tid] - M);
        size_t rg = (size_t)(m0 + tid);
        pm[rg * PARTS + nt] = M;
        ps[rg * PARTS + nt] = S;
    }
}

// Combine 125 partials per row -> lse -> masked lsm value. Grid MROWS blocks.
__global__ __launch_bounds__(256) void combine_loss(
    const float* __restrict__ pm, const float* __restrict__ ps,
    const float* __restrict__ gval, const int* __restrict__ trg_lens,
    float* __restrict__ nll_buf)
{
    int r = blockIdx.x, tid = threadIdx.x;
    int t = r >> 6, b_ = r & 63;
    __shared__ float red[256];
    const float* pmr = pm + (size_t)r * PARTS;
    const float* psr = ps + (size_t)r * PARTS;
    float m = -1e30f;
    for (int p = tid; p < 125; p += 256) m = fmaxf(m, pmr[p]);
    red[tid] = m; __syncthreads();
    for (int s = 128; s >= 1; s >>= 1) {
        if (tid < s) red[tid] = fmaxf(red[tid], red[tid + s]);
        __syncthreads();
    }
    m = red[0]; __syncthreads();
    float s = 0.f;
    for (int p = tid; p < 125; p += 256) s += psr[p] * expf(pmr[p] - m);
    red[tid] = s; __syncthreads();
    for (int st = 128; st >= 1; st >>= 1) {
        if (tid < st) red[tid] += red[tid + st];
        __syncthreads();
    }
    if (tid == 0) {
        float lse = m + logf(red[0]);
        nll_buf[r] = (t + 1 < trg_lens[b_]) ? (gval[r] - lse) : 0.f;
    }
}

__global__ void init_zero(ushort* hbf, float* cbuf)
{
    int idx = blockIdx.x * 256 + threadIdx.x;   // 131072 = 2*2*B*H
    hbf[idx] = 0;
    cbuf[idx] = 0.f;
}

__global__ __launch_bounds__(256) void write_out(const float* __restrict__ nll_buf,
                                                 float* __restrict__ out)
{
    __shared__ float red[256];
    float s = 0.f;
    for (int i = threadIdx.x; i < MROWS; i += 256) s += nll_buf[i];
    red[threadIdx.x] = s; __syncthreads();
    for (int st = 128; st >= 1; st >>= 1) {
        if (threadIdx.x < st) red[threadIdx.x] += red[threadIdx.x + st];
        __syncthreads();
    }
    if (threadIdx.x == 0) out[0] = red[0];
}

// ---------------------------------------------------------------------------
extern "C" void kernel_launch(void* const* d_in, const int* in_sizes, int n_in,
                              void* d_out, int out_size, void* d_ws, size_t ws_size,
                              hipStream_t stream)
{
    const int*   src_tokens = (const int*)d_in[0];
    const int*   src_lens   = (const int*)d_in[1];
    const int*   trg_tokens = (const int*)d_in[2];
    const int*   trg_lens   = (const int*)d_in[3];
    const float* src_emb    = (const float*)d_in[4];
    const float* trg_emb    = (const float*)d_in[5];
    const float* enc_Wih    = (const float*)d_in[6];
    const float* enc_Whh    = (const float*)d_in[7];
    const float* enc_b      = (const float*)d_in[8];
    const float* rev_Wih    = (const float*)d_in[9];
    const float* rev_Whh    = (const float*)d_in[10];
    const float* rev_b      = (const float*)d_in[11];
    const float* dec_Wih    = (const float*)d_in[12];
    const float* dec_Whh    = (const float*)d_in[13];
    const float* dec_b      = (const float*)d_in[14];
    const float* hid_W      = (const float*)d_in[15];
    const float* hid_b      = (const float*)d_in[16];
    const float* out_W      = (const float*)d_in[17];
    const float* out_b      = (const float*)d_in[18];
    const float* init_W     = (const float*)d_in[19];
    const float* init_b     = (const float*)d_in[20];

    char* ws = (char*)d_ws;
    size_t off = 0;
    auto alloc = [&](size_t bytes) -> void* {
        void* p = ws + off;
        off = (off + bytes + 255) & ~(size_t)255;
        return p;
    };
    // activations / state
    ushort* sv_bf    = (ushort*)alloc((size_t)TS * B * E * 2);        // 4.2 MB
    ushort* Henc_bf  = (ushort*)alloc((size_t)B * TS * DH * 2);       // 8.4 MB
    ushort* hbf      = (ushort*)alloc((size_t)2 * 2 * B * H * 2);     // enc ping-pong
    float*  cbuf     = (float*) alloc((size_t)2 * 2 * B * H * 4);
    ushort* final_bf = (ushort*)alloc((size_t)B * 4 * H * 2);
    float*  gates    = (float*) alloc((size_t)B * 4 * DH * 4);        // 1 MB
    float*  dec_c    = (float*) alloc((size_t)B * DH * 4);
    ushort* h0_bf    = (ushort*)alloc((size_t)B * DH * 2);
    ushort* xrow     = (ushort*)alloc((size_t)TT * B * XROW * 2);     // 21 MB
    ushort* av_out   = (ushort*)alloc((size_t)MROWS * DH * 2);        // 8.3 MB
    float*  pm       = (float*) alloc((size_t)MROWS * PARTS * 4);     // 2.1 MB
    float*  ps       = (float*) alloc((size_t)MROWS * PARTS * 4);     // 2.1 MB
    float*  gval     = (float*) alloc((size_t)MROWS * 4);
    float*  nll_buf  = (float*) alloc((size_t)MROWS * 4);
    float*  bias2    = (float*) alloc((size_t)4 * DH * 4);
    // bf16 weights
    ushort* w_eWih_f = (ushort*)alloc((size_t)4 * H * E * 2);
    ushort* w_eWhh_f = (ushort*)alloc((size_t)4 * H * H * 2);
    ushort* w_eWih_r = (ushort*)alloc((size_t)4 * H * E * 2);
    ushort* w_eWhh_r = (ushort*)alloc((size_t)4 * H * H * 2);
    ushort* w_dWih   = (ushort*)alloc((size_t)4 * DH * 1536 * 2);     // 12.6 MB
    ushort* w_dWhh   = (ushort*)alloc((size_t)4 * DH * DH * 2);       // 8.4 MB
    ushort* w_hid    = (ushort*)alloc((size_t)DH * 2 * DH * 2);       // 4 MB
    ushort* w_out    = (ushort*)alloc((size_t)VT * DH * 2);           // 65.5 MB
    ushort* w_init   = (ushort*)alloc((size_t)DH * 2 * DH * 2);       // 4 MB
    ushort* w_pack   = (ushort*)alloc((size_t)4 * DH * XROW * 2);     // 21 MB
    // transient: hid_W^T bf16 (4 MB) aliases av_out (8.3 MB, written much later)
    ushort* hidWT    = (ushort*)av_out;

    // ---- one-time precompute ----
    conv_bf16<<<512, 256, 0, stream>>>(enc_Wih, w_eWih_f, 4 * H * E / 4);
    conv_bf16<<<512, 256, 0, stream>>>(enc_Whh, w_eWhh_f, 4 * H * H / 4);
    conv_bf16<<<512, 256, 0, stream>>>(rev_Wih, w_eWih_r, 4 * H * E / 4);
    conv_bf16<<<512, 256, 0, stream>>>(rev_Whh, w_eWhh_r, 4 * H * H / 4);
    conv_bf16<<<512, 256, 0, stream>>>(dec_Wih, w_dWih, 4 * DH * 1536 / 4);
    conv_bf16<<<512, 256, 0, stream>>>(dec_Whh, w_dWhh, 4 * DH * DH / 4);
    conv_bf16<<<512, 256, 0, stream>>>(hid_W, w_hid, DH * 2 * DH / 4);
    conv_bf16<<<2048, 256, 0, stream>>>(out_W, w_out, VT * DH / 4);
    conv_bf16<<<512, 256, 0, stream>>>(init_W, w_init, DH * 2 * DH / 4);

    // hid_W^T bf16
    transp_hid<<<dim3(32, 16), 256, 0, stream>>>(hid_W, hidWT);
    // Wmod = Wv @ hid_W + [Whh | 0]  ->  w_pack[:, 512:2560]
    gemm_big<<<dim3(32, 64), 256, 0, stream>>>(
        w_dWih + 512, 1536, hidWT, 1024, 1024,
        nullptr, nullptr, 0, w_pack + 512, XROW, 0,
        w_dWhh, 1024, 1024);
    // We -> w_pack[:, :512]
    copy_we<<<512, 256, 0, stream>>>(w_dWih, w_pack);
    // bias2 = dec_b + Wv @ hid_b
    fold_bias<<<1024, 256, 0, stream>>>(dec_Wih, dec_b, hid_b, bias2);

    init_zero<<<2 * 2 * B * H / 256, 256, 0, stream>>>(hbf, cbuf);
    embed_src<<<B * TS, 256, 0, stream>>>(src_tokens, src_emb, sv_bf);
    embed_trg<<<B * TT, 256, 0, stream>>>(trg_tokens, trg_emb, xrow);

    // ---- encoder recurrence ----
    for (int t = 0; t < TS; t++) {
        int par = t & 1;
        enc_step<<<64, 256, 0, stream>>>(
            w_eWih_f, w_eWhh_f, enc_b, w_eWih_r, w_eWhh_r, rev_b, sv_bf,
            hbf + (size_t)par * 2 * B * H, hbf + (size_t)(par ^ 1) * 2 * B * H,
            cbuf + (size_t)par * 2 * B * H, cbuf + (size_t)(par ^ 1) * 2 * B * H,
            Henc_bf, final_bf, src_lens, t);
    }

    // c0 (f32) and h0 = tanh(c0) (bf16)
    gemm_big<<<dim3(16, 1), 256, 0, stream>>>(
        final_bf, 2 * DH, w_init, 2 * DH, 2 * DH,
        init_b, dec_c, DH, h0_bf, DH, 1, nullptr, 0, 0);

    // ---- decoder recurrence (2 kernels per step) ----
    for (int t = 0; t < TT - 1; t++) {
        if (t == 0) {
            dec_gates_t0<<<64, 256, 0, stream>>>(
                xrow, XROW, w_pack, h0_bf, DH, w_dWhh, DH, DH, dec_b, gates);
        } else {
            dec_gates3<<<256, 256, 0, stream>>>(
                xrow + (size_t)t * B * XROW, w_pack, bias2, gates);
        }
        dec_cell_attn<<<B, 512, 0, stream>>>(
            gates, dec_c, xrow + (size_t)(t + 1) * B * XROW, Henc_bf, src_lens);
    }

    // ---- batched av projection: av_out[r] = hid(hc[r]) ; hc = xrow[t+1][512:] ----
    gemm_big<<<dim3(16, MROWS / 64), 256, 0, stream>>>(
        xrow + (size_t)B * XROW + 512, XROW, w_hid, 2 * DH, 2 * DH,
        hid_b, nullptr, 0, av_out, DH, 0, nullptr, 0, 0);

    // ---- batched output projection + fused loss partials ----
    out_loss_b<<<dim3(MROWS / 64, VT / 64 / 4), 256, 0, stream>>>(
        av_out, w_out, out_b, trg_tokens, pm, ps, gval);
    combine_loss<<<MROWS, 256, 0, stream>>>(pm, ps, gval, trg_lens, nll_buf);
    write_out<<<1, 256, 0, stream>>>(nll_buf, (float*)d_out);
}

// Round 5
// 3628.428 us; speedup vs baseline: 6.6974x; 1.2827x over previous
//
#include <hip/hip_runtime.h>
#include <math.h>

#define B   64
#define TS  64
#define TT  64
#define E   512
#define H   512
#define DH  1024
#define VT  32000
#define MROWS ((TT - 1) * B)      // 4032 real rows; padded to 4096 for 128-tiles
#define MPAD 4096
#define PARTS 256                 // stride for loss partials (250 used)
#define XROW 2560                 // [emb(512) | h(1024) | ctx(1024)]

typedef __attribute__((ext_vector_type(8))) short short8;
typedef __attribute__((ext_vector_type(4))) float floatx4;

__device__ __forceinline__ ushort f2bf(float f) {
    union { float f; unsigned int i; } v; v.f = f;
    unsigned int u = v.i;
    return (ushort)((u + 0x7fffu + ((u >> 16) & 1u)) >> 16);
}
__device__ __forceinline__ float bf2f(ushort u) {
    union { unsigned int i; float f; } v; v.i = ((unsigned int)u) << 16;
    return v.f;
}
__device__ __forceinline__ short8 ld8h(const ushort* p) {
    return *(const short8*)p;
}
__device__ __forceinline__ float sigm(float x) { return 1.0f / (1.0f + expf(-x)); }

// ---------------------------------------------------------------------------
__global__ void conv_bf16(const float* __restrict__ src, ushort* __restrict__ dst, int n4)
{
    int i = blockIdx.x * 256 + threadIdx.x;
    int stride = gridDim.x * 256;
    for (; i < n4; i += stride) {
        float4 v = ((const float4*)src)[i];
        ushort4 o;
        o.x = f2bf(v.x); o.y = f2bf(v.y); o.z = f2bf(v.z); o.w = f2bf(v.w);
        ((ushort4*)dst)[i] = o;
    }
}

// transpose hid_W f32 [1024][2048] -> bf16 [2048][1024]
__global__ __launch_bounds__(256) void transp_hid(const float* __restrict__ src,
                                                  ushort* __restrict__ dst)
{
    __shared__ float t[64][65];
    int i0 = blockIdx.x * 64;
    int j0 = blockIdx.y * 64;
    int c = threadIdx.x & 63, rr = threadIdx.x >> 6;
#pragma unroll
    for (int p = 0; p < 16; p++) {
        int r = rr + p * 4;
        t[r][c] = src[(size_t)(j0 + r) * 2048 + i0 + c];
    }
    __syncthreads();
#pragma unroll
    for (int p = 0; p < 16; p++) {
        int r = rr + p * 4;
        dst[(size_t)(i0 + r) * 1024 + j0 + c] = f2bf(t[c][r]);
    }
}

// bias2[m] = dec_b[m] + sum_j hid_b[j] * dec_Wih[m][512+j]
__global__ __launch_bounds__(256) void fold_bias(const float* __restrict__ dec_Wih,
                                                 const float* __restrict__ dec_b,
                                                 const float* __restrict__ hid_b,
                                                 float* __restrict__ bias2)
{
    int wave = threadIdx.x >> 6, lane = threadIdx.x & 63;
    int row = blockIdx.x * 4 + wave;
    float s = 0.f;
    for (int k = 0; k < 16; k++) {
        int j = lane + k * 64;
        s += hid_b[j] * dec_Wih[(size_t)row * 1536 + 512 + j];
    }
    for (int off = 32; off >= 1; off >>= 1) s += __shfl_xor(s, off);
    if (lane == 0) bias2[row] = dec_b[row] + s;
}

// ---------------------------------------------------------------------------
// Batched GEMM: C[m][n] = sum_k A[m*lda+k]*W[n*ldw+k]. Block tile 64x256,
// 4 waves along N, wave tile 64x64 (4x4 frags). grid=(N/256, M/64).
// MFMA layouts (HW-verified m89).
// ---------------------------------------------------------------------------
__global__ __launch_bounds__(256) void gemm_big(
    const ushort* __restrict__ A, int lda,
    const ushort* __restrict__ W, int ldw, int K,
    const float* __restrict__ bias,
    float* __restrict__ outf, int ldof,
    ushort* __restrict__ outb, int ldob, int do_tanh,
    const ushort* __restrict__ addp, int ldadd, int addN)
{
    const int tid  = threadIdx.x;
    const int wave = tid >> 6, lane = tid & 63;
    const int l15 = lane & 15, quad = lane >> 4;
    const int m0 = blockIdx.y * 64;
    const int n0 = blockIdx.x * 256 + wave * 64;
    const int koff = quad * 8;

    floatx4 acc[4][4] = {};
    const ushort* Ap = A + (size_t)(m0 + l15) * lda + koff;
    const ushort* Wp = W + (size_t)(n0 + l15) * ldw + koff;
#pragma unroll 2
    for (int kb = 0; kb < K; kb += 32) {
        short8 a[4], w[4];
#pragma unroll
        for (int mi = 0; mi < 4; mi++) a[mi] = ld8h(Ap + (size_t)mi * 16 * lda + kb);
#pragma unroll
        for (int nj = 0; nj < 4; nj++) w[nj] = ld8h(Wp + (size_t)nj * 16 * ldw + kb);
#pragma unroll
        for (int mi = 0; mi < 4; mi++)
#pragma unroll
            for (int nj = 0; nj < 4; nj++)
                acc[mi][nj] = __builtin_amdgcn_mfma_f32_16x16x32_bf16(
                    a[mi], w[nj], acc[mi][nj], 0, 0, 0);
    }
    for (int mi = 0; mi < 4; mi++)
        for (int nj = 0; nj < 4; nj++) {
            int col = n0 + nj * 16 + l15;
            float bv = bias ? bias[col] : 0.0f;
            for (int r = 0; r < 4; r++) {
                int row = m0 + mi * 16 + quad * 4 + r;
                float v = acc[mi][nj][r] + bv;
                if (addp && col < addN) v += bf2f(addp[(size_t)row * ldadd + col]);
                if (outf) outf[(size_t)row * ldof + col] = v;
                if (outb) outb[(size_t)row * ldob + col] = f2bf(do_tanh ? tanhf(v) : v);
            }
        }
}

// ---------------------------------------------------------------------------
// Encoder step (xW precomputed): gates = xW[t] + h_prev@Whh^T + b, then cell.
// Grid: 64 blocks x 1024 thr (dir=bid>>5, jt=bid&31).
// 16 waves = 4 gates x 4 K-splits of 128; LDS reduce; fused cell epilogue.
// ---------------------------------------------------------------------------
__global__ __launch_bounds__(1024) void enc_step(
    const ushort* __restrict__ Whh_f, const float* __restrict__ bias_f,
    const ushort* __restrict__ Whh_r, const float* __restrict__ bias_r,
    const float* __restrict__ xW,                        // [(t*B+b)][4096] f32
    const ushort* __restrict__ hprev, ushort* __restrict__ hnext,  // [dir][B][H]
    const float* __restrict__ cprev, float* __restrict__ cnext,
    ushort* __restrict__ Henc_bf, ushort* __restrict__ final_bf,
    const int* __restrict__ src_lens, int t)
{
    const int d  = blockIdx.x >> 5;
    const int jt = blockIdx.x & 31;
    const int tid = threadIdx.x;
    const int wave = tid >> 6, lane = tid & 63;
    const int g = wave >> 2, ks = wave & 3;
    const int l15 = lane & 15, quad = lane >> 4;
    const ushort* Whh  = d ? Whh_r : Whh_f;
    const float*  bias = d ? bias_r : bias_f;
    const ushort* hp = hprev + (size_t)d * (B * H) + ks * 128;
    const int n0 = g * H + jt * 16;
    const int koff = quad * 8;

    floatx4 acc[4] = {};
    const ushort* Wp = Whh + (size_t)(n0 + l15) * H + ks * 128 + koff;
#pragma unroll
    for (int kb = 0; kb < 128; kb += 32) {
        short8 w = ld8h(Wp + kb);
#pragma unroll
        for (int mi = 0; mi < 4; mi++) {
            short8 a = ld8h(hp + (size_t)(mi * 16 + l15) * H + kb + koff);
            acc[mi] = __builtin_amdgcn_mfma_f32_16x16x32_bf16(a, w, acc[mi], 0, 0, 0);
        }
    }
    __shared__ float part[4][4][B][16];        // 64 KB
#pragma unroll
    for (int mi = 0; mi < 4; mi++)
#pragma unroll
        for (int r = 0; r < 4; r++)
            part[g][ks][mi * 16 + quad * 4 + r][l15] = acc[mi][r];
    __syncthreads();

    int b_ = tid >> 4, jl = tid & 15;          // 1024 threads = 64 x 16
    int j = jt * 16 + jl;
    const float* xwr = xW + ((size_t)(t * B + b_)) * 4096 + d * 2048;
    float g4[4];
#pragma unroll
    for (int g2 = 0; g2 < 4; g2++)
        g4[g2] = part[g2][0][b_][jl] + part[g2][1][b_][jl]
               + part[g2][2][b_][jl] + part[g2][3][b_][jl]
               + bias[g2 * 512 + jt * 16 + jl] + xwr[g2 * 512 + jt * 16 + jl];
    float cp = cprev[((size_t)d * B + b_) * H + j];
    float cn = sigm(g4[1]) * cp + sigm(g4[0]) * tanhf(g4[2]);
    float hn = sigm(g4[3]) * tanhf(cn);
    cnext[((size_t)d * B + b_) * H + j] = cn;
    hnext[((size_t)d * B + b_) * H + j] = f2bf(hn);
    Henc_bf[(size_t)(b_ * TS + t) * DH + d * H + j] = f2bf(hn);
    if (t == src_lens[b_] - 1) {
        final_bf[b_ * (4 * H) + d * H + j] = f2bf(hn);
        final_bf[b_ * (4 * H) + 2 * H + d * H + j] = f2bf(cn);
    }
}

// ---------------------------------------------------------------------------
// Decoder gates (embW precomputed): gates = embW[t] + A@W^T + bias.
// t==0: A=h0 (K2=1024, W=Whh);  t>=1: A=xrow[t]+512 (K2=2048, W=Wmod).
// Grid 256 blocks x 512 thr: block = 16 cols, 8 waves K-split; LDS reduce.
// ---------------------------------------------------------------------------
__global__ __launch_bounds__(512) void dec_gates3(
    const ushort* __restrict__ A, int lda,
    const ushort* __restrict__ W, int ldw, int K2,
    const float* __restrict__ bias, const float* __restrict__ embW_t,
    float* __restrict__ gates)
{
    const int tid = threadIdx.x;
    const int wave = tid >> 6, lane = tid & 63;
    const int l15 = lane & 15, quad = lane >> 4;
    const int n0 = blockIdx.x * 16;
    const int kper = K2 >> 3;                  // 256 (t>=1) / 128 (t0)
    const int k0 = wave * kper;
    const int koff = quad * 8;

    floatx4 acc[4] = {};
    const ushort* Ap = A + (size_t)l15 * lda + k0 + koff;
    const ushort* Wp = W + (size_t)(n0 + l15) * ldw + k0 + koff;
#pragma unroll 2
    for (int kb = 0; kb < kper; kb += 32) {
        short8 w = ld8h(Wp + kb);
#pragma unroll
        for (int mi = 0; mi < 4; mi++) {
            short8 a = ld8h(Ap + (size_t)mi * 16 * lda + kb);
            acc[mi] = __builtin_amdgcn_mfma_f32_16x16x32_bf16(a, w, acc[mi], 0, 0, 0);
        }
    }
    __shared__ float part[8][B][16];           // 32 KB
#pragma unroll
    for (int mi = 0; mi < 4; mi++)
#pragma unroll
        for (int r = 0; r < 4; r++)
            part[wave][mi * 16 + quad * 4 + r][l15] = acc[mi][r];
    __syncthreads();
    for (int p = tid; p < B * 16; p += 512) {
        int b_ = p >> 4, jl = p & 15;
        float v = bias[n0 + jl] + embW_t[(size_t)b_ * 4096 + n0 + jl];
#pragma unroll
        for (int w8 = 0; w8 < 8; w8++) v += part[w8][b_][jl];
        gates[(size_t)b_ * (4 * DH) + n0 + jl] = v;
    }
}

// ---------------------------------------------------------------------------
__global__ void embed_src(const int* __restrict__ toks, const float* __restrict__ emb,
                          ushort* __restrict__ sv)
{
    int bt = blockIdx.x;                 // b*64 + t
    int b_ = bt >> 6, t = bt & 63;
    int tok = toks[bt];
    const float* src = emb + (size_t)tok * E;
    ushort* dst = sv + ((size_t)t * B + b_) * E;
    for (int e = threadIdx.x; e < E; e += 256) dst[e] = f2bf(src[e]);
}

__global__ void embed_trg(const int* __restrict__ toks, const float* __restrict__ emb,
                          ushort* __restrict__ xrow)
{
    int bt = blockIdx.x;
    int b_ = bt >> 6, t = bt & 63;
    int tok = toks[bt];
    const float* src = emb + (size_t)tok * E;
    ushort* dst = xrow + ((size_t)t * B + b_) * XROW;
    for (int e = threadIdx.x; e < E; e += 256) dst[e] = f2bf(src[e]);
}

// ---------------------------------------------------------------------------
// Fused decoder cell + attention (512 thr, one block per batch row).
// h -> xnext[512:1536], ctx -> xnext[1536:2560].
// ---------------------------------------------------------------------------
__global__ __launch_bounds__(512) void dec_cell_attn(
    const float* __restrict__ gates, float* __restrict__ c,
    ushort* __restrict__ xnext,
    const ushort* __restrict__ Henc_bf, const int* __restrict__ src_lens)
{
    int b_ = blockIdx.x, tid = threadIdx.x;
    __shared__ float hsm[DH];
    __shared__ float red[512];
    __shared__ float attn[TS];
    const float* g = gates + (size_t)b_ * 4 * DH;
    for (int j = tid; j < DH; j += 512) {
        float cn = sigm(g[DH + j]) * c[(size_t)b_ * DH + j]
                 + sigm(g[j]) * tanhf(g[2 * DH + j]);
        c[(size_t)b_ * DH + j] = cn;
        float hn = sigm(g[3 * DH + j]) * tanhf(cn);
        hsm[j] = hn;
        xnext[(size_t)b_ * XROW + 512 + j] = f2bf(hn);
    }
    __syncthreads();
    int tq = tid & 63, part = tid >> 6;
    const ushort* He = Henc_bf + (size_t)(b_ * TS + tq) * DH + part * 128;
    const float* hh = hsm + part * 128;
    float pp = 0.f;
#pragma unroll
    for (int jj = 0; jj < 128; jj += 8) {
        short8 hv = ld8h(He + jj);
#pragma unroll
        for (int k = 0; k < 8; k++) pp += bf2f((ushort)hv[k]) * hh[jj + k];
    }
    red[tid] = pp;
    __syncthreads();
    if (tid < 64) {
        float s = 0.f;
#pragma unroll
        for (int p = 0; p < 8; p++) s += red[tid + p * 64];
        if (tid >= src_lens[b_]) s = -1e9f;
        float m = s;
        for (int off = 32; off >= 1; off >>= 1) m = fmaxf(m, __shfl_xor(m, off));
        float e = expf(s - m);
        float sum = e;
        for (int off = 32; off >= 1; off >>= 1) sum += __shfl_xor(sum, off);
        attn[tid] = e / sum;
    }
    __syncthreads();
#pragma unroll
    for (int k = 0; k < 2; k++) {
        int j = k * 512 + tid;
        float a = 0.f;
#pragma unroll 8
        for (int t2 = 0; t2 < TS; t2++)
            a += attn[t2] * bf2f(Henc_bf[(size_t)(b_ * TS + t2) * DH + j]);
        xnext[(size_t)b_ * XROW + 1536 + j] = f2bf(a);
    }
}

// ---------------------------------------------------------------------------
// Output projection + loss partials, m97-style: 128x128 tile, BK=64,
// double-buffered LDS (reg-staged, XOR-swizzled: slot ^= row&7), 4 waves
// each 64x64 (4x4 frags). grid = (32 m-tiles, 250 n-tiles), m fastest.
// ---------------------------------------------------------------------------
__global__ __launch_bounds__(256) void out_loss_m97(
    const ushort* __restrict__ A,        // av_out [MPAD][DH]
    const ushort* __restrict__ W,        // out_W bf16 [VT][DH]
    const float* __restrict__ bias,
    const int* __restrict__ trg_tokens,
    float* __restrict__ pm, float* __restrict__ ps, float* __restrict__ gval)
{
    const int tid = threadIdx.x;
    const int wave = tid >> 6, lane = tid & 63;
    const int wm = wave >> 1, wn = wave & 1;
    const int l15 = lane & 15, quad = lane >> 4;
    const int mt = blockIdx.x, nt = blockIdx.y;
    const int m0 = mt * 128, n0g = nt * 128;

    __shared__ short8 lA[2][1024];       // [128 rows][128B], swizzled, 16KB each
    __shared__ short8 lB[2][1024];
    __shared__ int   gsm[128];
    __shared__ float lm[2][128], ls[2][128];

    if (tid < 128) {
        int r = m0 + tid;
        int tt = r >> 6, b_ = r & 63;
        gsm[tid] = (tt < TT - 1) ? trg_tokens[b_ * TT + tt + 1] : -1;
    }

    const int srow = tid >> 3, sslot = tid & 7;   // stage: 4 rounds x (row,slot)
    short8 ra[4], rb[4];

    auto load_tile = [&](int kb) {
#pragma unroll
        for (int rr = 0; rr < 4; rr++) {
            int row = srow + rr * 32;
            ra[rr] = ld8h(A + (size_t)(m0 + row) * DH + kb + sslot * 8);
            rb[rr] = ld8h(W + (size_t)(n0g + row) * DH + kb + sslot * 8);
        }
    };
    auto write_tile = [&](int buf) {
#pragma unroll
        for (int rr = 0; rr < 4; rr++) {
            int row = srow + rr * 32;
            int idx = row * 8 + (sslot ^ (row & 7));     // short8 units
            lA[buf][idx] = ra[rr];
            lB[buf][idx] = rb[rr];
        }
    };

    floatx4 acc[4][4] = {};
    load_tile(0);
    write_tile(0);
    __syncthreads();

    for (int ko = 0; ko < DH / 64; ko++) {       // 16 outer K-steps
        int cur = ko & 1;
        if (ko + 1 < DH / 64) load_tile((ko + 1) * 64);
#pragma unroll
        for (int kh = 0; kh < 2; kh++) {
            short8 av[4], wv[4];
#pragma unroll
            for (int mi = 0; mi < 4; mi++) {
                int row = wm * 64 + mi * 16 + l15;
                av[mi] = lA[cur][row * 8 + ((kh * 4 + quad) ^ (row & 7))];
            }
#pragma unroll
            for (int nj = 0; nj < 4; nj++) {
                int row = wn * 64 + nj * 16 + l15;
                wv[nj] = lB[cur][row * 8 + ((kh * 4 + quad) ^ (row & 7))];
            }
#pragma unroll
            for (int mi = 0; mi < 4; mi++)
#pragma unroll
                for (int nj = 0; nj < 4; nj++)
                    acc[mi][nj] = __builtin_amdgcn_mfma_f32_16x16x32_bf16(
                        av[mi], wv[nj], acc[mi][nj], 0, 0, 0);
        }
        if (ko + 1 < DH / 64) write_tile(cur ^ 1);
        __syncthreads();
    }

    // epilogue: per-row max & sumexp over this 128-col block
    for (int mi = 0; mi < 4; mi++) {
        float v[4][4];
#pragma unroll
        for (int nj = 0; nj < 4; nj++) {
            int col = n0g + wn * 64 + nj * 16 + l15;
            float bv = bias[col];
#pragma unroll
            for (int r = 0; r < 4; r++) {
                v[nj][r] = acc[mi][nj][r] + bv;
                int lr = wm * 64 + mi * 16 + quad * 4 + r;
                if (col == gsm[lr]) gval[m0 + lr] = v[nj][r];
            }
        }
#pragma unroll
        for (int r = 0; r < 4; r++) {
            float mx = fmaxf(fmaxf(v[0][r], v[1][r]), fmaxf(v[2][r], v[3][r]));
#pragma unroll
            for (int off = 1; off < 16; off <<= 1) mx = fmaxf(mx, __shfl_xor(mx, off));
            float s = expf(v[0][r] - mx) + expf(v[1][r] - mx)
                    + expf(v[2][r] - mx) + expf(v[3][r] - mx);
#pragma unroll
            for (int off = 1; off < 16; off <<= 1) s += __shfl_xor(s, off);
            if (l15 == 0) {
                int lr = wm * 64 + mi * 16 + quad * 4 + r;
                lm[wn][lr] = mx; ls[wn][lr] = s;
            }
        }
    }
    __syncthreads();
    if (tid < 128) {
        float M = fmaxf(lm[0][tid], lm[1][tid]);
        float S = ls[0][tid] * expf(lm[0][tid] - M) + ls[1][tid] * expf(lm[1][tid] - M);
        size_t rg = (size_t)(m0 + tid);
        pm[rg * PARTS + nt] = M;
        ps[rg * PARTS + nt] = S;
    }
}

// Combine 250 partials per row -> lse -> masked lsm value. Grid MROWS blocks.
__global__ __launch_bounds__(256) void combine_loss(
    const float* __restrict__ pm, const float* __restrict__ ps,
    const float* __restrict__ gval, const int* __restrict__ trg_lens,
    float* __restrict__ nll_buf)
{
    int r = blockIdx.x, tid = threadIdx.x;
    int t = r >> 6, b_ = r & 63;
    __shared__ float red[256];
    const float* pmr = pm + (size_t)r * PARTS;
    const float* psr = ps + (size_t)r * PARTS;
    float m = -1e30f;
    for (int p = tid; p < 250; p += 256) m = fmaxf(m, pmr[p]);
    red[tid] = m; __syncthreads();
    for (int s = 128; s >= 1; s >>= 1) {
        if (tid < s) red[tid] = fmaxf(red[tid], red[tid + s]);
        __syncthreads();
    }
    m = red[0]; __syncthreads();
    float s = 0.f;
    for (int p = tid; p < 250; p += 256) s += psr[p] * expf(pmr[p] - m);
    red[tid] = s; __syncthreads();
    for (int st = 128; st >= 1; st >>= 1) {
        if (tid < st) red[tid] += red[tid + st];
        __syncthreads();
    }
    if (tid == 0) {
        float lse = m + logf(red[0]);
        nll_buf[r] = (t + 1 < trg_lens[b_]) ? (gval[r] - lse) : 0.f;
    }
}

__global__ void init_zero(ushort* hbf, float* cbuf, ushort* av_tail)
{
    int idx = blockIdx.x * 256 + threadIdx.x;   // 131072 = 2*2*B*H
    hbf[idx] = 0;
    cbuf[idx] = 0.f;
    if (idx < 64 * DH) av_tail[idx] = 0;        // av_out pad rows 4032..4095
}

__global__ __launch_bounds__(256) void write_out(const float* __restrict__ nll_buf,
                                                 float* __restrict__ out)
{
    __shared__ float red[256];
    float s = 0.f;
    for (int i = threadIdx.x; i < MROWS; i += 256) s += nll_buf[i];
    red[threadIdx.x] = s; __syncthreads();
    for (int st = 128; st >= 1; st >>= 1) {
        if (threadIdx.x < st) red[threadIdx.x] += red[threadIdx.x + st];
        __syncthreads();
    }
    if (threadIdx.x == 0) out[0] = red[0];
}

// ---------------------------------------------------------------------------
extern "C" void kernel_launch(void* const* d_in, const int* in_sizes, int n_in,
                              void* d_out, int out_size, void* d_ws, size_t ws_size,
                              hipStream_t stream)
{
    const int*   src_tokens = (const int*)d_in[0];
    const int*   src_lens   = (const int*)d_in[1];
    const int*   trg_tokens = (const int*)d_in[2];
    const int*   trg_lens   = (const int*)d_in[3];
    const float* src_emb    = (const float*)d_in[4];
    const float* trg_emb    = (const float*)d_in[5];
    const float* enc_Wih    = (const float*)d_in[6];
    const float* enc_Whh    = (const float*)d_in[7];
    const float* enc_b      = (const float*)d_in[8];
    const float* rev_Wih    = (const float*)d_in[9];
    const float* rev_Whh    = (const float*)d_in[10];
    const float* rev_b      = (const float*)d_in[11];
    const float* dec_Wih    = (const float*)d_in[12];
    const float* dec_Whh    = (const float*)d_in[13];
    const float* dec_b      = (const float*)d_in[14];
    const float* hid_W      = (const float*)d_in[15];
    const float* hid_b      = (const float*)d_in[16];
    const float* out_W      = (const float*)d_in[17];
    const float* out_b      = (const float*)d_in[18];
    const float* init_W     = (const float*)d_in[19];
    const float* init_b     = (const float*)d_in[20];

    char* ws = (char*)d_ws;
    size_t off = 0;
    auto alloc = [&](size_t bytes) -> void* {
        void* p = ws + off;
        off = (off + bytes + 255) & ~(size_t)255;
        return p;
    };
    // activations / state
    ushort* sv_bf    = (ushort*)alloc((size_t)TS * B * E * 2);
    ushort* Henc_bf  = (ushort*)alloc((size_t)B * TS * DH * 2);
    ushort* hbf      = (ushort*)alloc((size_t)2 * 2 * B * H * 2);
    float*  cbuf     = (float*) alloc((size_t)2 * 2 * B * H * 4);
    ushort* final_bf = (ushort*)alloc((size_t)B * 4 * H * 2);
    float*  gates    = (float*) alloc((size_t)B * 4 * DH * 4);
    float*  dec_c    = (float*) alloc((size_t)B * DH * 4);
    ushort* h0_bf    = (ushort*)alloc((size_t)B * DH * 2);
    ushort* xrow     = (ushort*)alloc((size_t)TT * B * XROW * 2);       // 21 MB
    ushort* av_out   = (ushort*)alloc((size_t)MPAD * DH * 2);           // 8.4 MB
    float*  pm       = (float*) alloc((size_t)MPAD * PARTS * 4);        // 4.2 MB
    float*  ps       = (float*) alloc((size_t)MPAD * PARTS * 4);        // 4.2 MB
    float*  gval     = (float*) alloc((size_t)MPAD * 4);
    float*  nll_buf  = (float*) alloc((size_t)MROWS * 4);
    float*  bias2    = (float*) alloc((size_t)4 * DH * 4);
    float*  pregates = (float*) alloc((size_t)4096 * 4096 * 4);         // 67 MB (xW / embW)
    // bf16 weights
    ushort* w_eWih_f = (ushort*)alloc((size_t)4 * H * E * 2);
    ushort* w_eWhh_f = (ushort*)alloc((size_t)4 * H * H * 2);
    ushort* w_eWih_r = (ushort*)alloc((size_t)4 * H * E * 2);
    ushort* w_eWhh_r = (ushort*)alloc((size_t)4 * H * H * 2);
    ushort* w_dWih   = (ushort*)alloc((size_t)4 * DH * 1536 * 2);
    ushort* w_dWhh   = (ushort*)alloc((size_t)4 * DH * DH * 2);
    ushort* w_hid    = (ushort*)alloc((size_t)DH * 2 * DH * 2);
    ushort* w_out    = (ushort*)alloc((size_t)VT * DH * 2);             // 65.5 MB
    ushort* w_init   = (ushort*)alloc((size_t)DH * 2 * DH * 2);
    ushort* w_pack   = (ushort*)alloc((size_t)4 * DH * XROW * 2);       // 21 MB (cols 512: Wmod)
    ushort* hidWT    = (ushort*)alloc((size_t)2 * DH * DH * 2);         // 4.2 MB

    // ---- one-time precompute ----
    conv_bf16<<<512, 256, 0, stream>>>(enc_Wih, w_eWih_f, 4 * H * E / 4);
    conv_bf16<<<512, 256, 0, stream>>>(enc_Whh, w_eWhh_f, 4 * H * H / 4);
    conv_bf16<<<512, 256, 0, stream>>>(rev_Wih, w_eWih_r, 4 * H * E / 4);
    conv_bf16<<<512, 256, 0, stream>>>(rev_Whh, w_eWhh_r, 4 * H * H / 4);
    conv_bf16<<<512, 256, 0, stream>>>(dec_Wih, w_dWih, 4 * DH * 1536 / 4);
    conv_bf16<<<512, 256, 0, stream>>>(dec_Whh, w_dWhh, 4 * DH * DH / 4);
    conv_bf16<<<512, 256, 0, stream>>>(hid_W, w_hid, DH * 2 * DH / 4);
    conv_bf16<<<2048, 256, 0, stream>>>(out_W, w_out, VT * DH / 4);
    conv_bf16<<<512, 256, 0, stream>>>(init_W, w_init, DH * 2 * DH / 4);

    transp_hid<<<dim3(32, 16), 256, 0, stream>>>(hid_W, hidWT);
    // Wmod = Wv @ hid_W + [Whh | 0]  ->  w_pack[:, 512:2560]
    gemm_big<<<dim3(8, 64), 256, 0, stream>>>(
        w_dWih + 512, 1536, hidWT, 1024, 1024,
        nullptr, nullptr, 0, w_pack + 512, XROW, 0,
        w_dWhh, 1024, 1024);
    fold_bias<<<1024, 256, 0, stream>>>(dec_Wih, dec_b, hid_b, bias2);

    init_zero<<<512, 256, 0, stream>>>(hbf, cbuf, av_out + (size_t)MROWS * DH);
    embed_src<<<B * TS, 256, 0, stream>>>(src_tokens, src_emb, sv_bf);
    embed_trg<<<B * TT, 256, 0, stream>>>(trg_tokens, trg_emb, xrow);

    // xW (encoder input projections, both dirs) -> pregates f32 [4096][4096]
    gemm_big<<<dim3(8, 64), 256, 0, stream>>>(
        sv_bf, E, w_eWih_f, E, E, nullptr, pregates, 4096,
        nullptr, 0, 0, nullptr, 0, 0);
    gemm_big<<<dim3(8, 64), 256, 0, stream>>>(
        sv_bf, E, w_eWih_r, E, E, nullptr, pregates + 2048, 4096,
        nullptr, 0, 0, nullptr, 0, 0);

    // ---- encoder recurrence (1 kernel/step, h-GEMM only) ----
    for (int t = 0; t < TS; t++) {
        int par = t & 1;
        enc_step<<<64, 1024, 0, stream>>>(
            w_eWhh_f, enc_b, w_eWhh_r, rev_b, pregates,
            hbf + (size_t)par * 2 * B * H, hbf + (size_t)(par ^ 1) * 2 * B * H,
            cbuf + (size_t)par * 2 * B * H, cbuf + (size_t)(par ^ 1) * 2 * B * H,
            Henc_bf, final_bf, src_lens, t);
    }

    // c0 (f32) and h0 = tanh(c0) (bf16)
    gemm_big<<<dim3(4, 1), 256, 0, stream>>>(
        final_bf, 2 * DH, w_init, 2 * DH, 2 * DH,
        init_b, dec_c, DH, h0_bf, DH, 1, nullptr, 0, 0);

    // embW (decoder emb projections) -> pregates f32 [4032][4096] (reuses buffer)
    gemm_big<<<dim3(16, 63), 256, 0, stream>>>(
        xrow, XROW, w_dWih, 1536, E, nullptr, pregates, 4096,
        nullptr, 0, 0, nullptr, 0, 0);

    // ---- decoder recurrence (2 kernels/step) ----
    for (int t = 0; t < TT - 1; t++) {
        if (t == 0) {
            dec_gates3<<<256, 512, 0, stream>>>(
                h0_bf, DH, w_dWhh, DH, DH, dec_b, pregates, gates);
        } else {
            dec_gates3<<<256, 512, 0, stream>>>(
                xrow + (size_t)t * B * XROW + 512, XROW,
                w_pack + 512, XROW, 2 * DH, bias2,
                pregates + (size_t)t * B * 4096, gates);
        }
        dec_cell_attn<<<B, 512, 0, stream>>>(
            gates, dec_c, xrow + (size_t)(t + 1) * B * XROW, Henc_bf, src_lens);
    }

    // ---- batched av projection: av_out[r] = hid(hc[r]) ----
    gemm_big<<<dim3(4, 63), 256, 0, stream>>>(
        xrow + (size_t)B * XROW + 512, XROW, w_hid, 2 * DH, 2 * DH,
        hid_b, nullptr, 0, av_out, DH, 0, nullptr, 0, 0);

    // ---- batched output projection + fused loss partials ----
    out_loss_m97<<<dim3(MPAD / 128, VT / 128), 256, 0, stream>>>(
        av_out, w_out, out_b, trg_tokens, pm, ps, gval);
    combine_loss<<<MROWS, 256, 0, stream>>>(pm, ps, gval, trg_lens, nll_buf);
    write_out<<<1, 256, 0, stream>>>(nll_buf, (float*)d_out);
}